// Round 10
// baseline (505.565 us; speedup 1.0000x reference)
//
#include <hip/hip_runtime.h>

#define NN 100000
#define EE 1600000
#define EPS 1e-5f
#define NBLK 196   // ceil(NN/512)
#define HBLK 1563  // ceil(EE/4/256)

__device__ __forceinline__ ushort f2bf(float f) {
    uint u = __float_as_uint(f);
    uint r = (u + 0x7FFF + ((u >> 16) & 1)) >> 16;  // RNE
    return (ushort)r;
}
__device__ __forceinline__ float bf2f(ushort u) {
    return __uint_as_float(((uint)u) << 16);
}

// ---------------- fill zero (float4 grid-stride) ----------------
__global__ void fill0(float4* __restrict__ p, long n4) {
    long i = (long)blockIdx.x * blockDim.x + threadIdx.x;
    long stride = (long)gridDim.x * blockDim.x;
    float4 z = make_float4(0.f, 0.f, 0.f, 0.f);
    for (; i < n4; i += stride) p[i] = z;
}

// ---------------- k1h: x1g = bf16(X@W1_1) (8 nodes/block, wave-local staging,
//                  NO barrier) + fused hist/rank ----------------
__global__ __launch_bounds__(256) void k1h(const float* __restrict__ X,
                                           const float* __restrict__ W1,
                                           ushort* __restrict__ x1g,
                                           const int* __restrict__ ei0, const int* __restrict__ ei1,
                                           int* __restrict__ deg0, int* __restrict__ deg1,
                                           int* __restrict__ rank0, int* __restrict__ rank1) {
    // hist part: first HBLK blocks, 4 edges/thread/list; atomic returns feed only stores.
    long ce = (long)blockIdx.x * 256 + threadIdx.x;
    if (blockIdx.x < HBLK && ce < EE / 4) {
        long i = ce * 4;
        int4 d0 = *reinterpret_cast<const int4*>(&ei0[EE + i]);
        int4 rk;
        rk.x = atomicAdd(&deg0[d0.x], 1);
        rk.y = atomicAdd(&deg0[d0.y], 1);
        rk.z = atomicAdd(&deg0[d0.z], 1);
        rk.w = atomicAdd(&deg0[d0.w], 1);
        *reinterpret_cast<int4*>(&rank0[i]) = rk;
        int4 d1 = *reinterpret_cast<const int4*>(&ei1[EE + i]);
        int4 rk1;
        rk1.x = atomicAdd(&deg1[d1.x], 1);
        rk1.y = atomicAdd(&deg1[d1.y], 1);
        rk1.z = atomicAdd(&deg1[d1.z], 1);
        rk1.w = atomicAdd(&deg1[d1.w], 1);
        *reinterpret_cast<int4*>(&rank1[i]) = rk1;
    }
    // GEMM: block = 8 nodes = 4 waves * 2? -> 2 waves * 4 nodes, wave-private LDS,
    // no __syncthreads (each wave writes then reads only its own region).
    __shared__ __align__(16) float Xs[4][16][132];  // [wave][n_loc*4+b][c]
    int t = threadIdx.x;
    int w = t >> 6, lane = t & 63;
    int nb = blockIdx.x * 16;          // 16 nodes/block (4 waves x 4 nodes)
    int nw = nb + w * 4;               // this wave's first node
#pragma unroll
    for (int i = 0; i < 8; ++i) {
        int flat = i * 64 + lane;      // (n_loc:2b, b:2b, c4:5b) = 4*4*32
        int n_loc = flat >> 7;
        int b = (flat >> 5) & 3;
        int c4 = (flat & 31) << 2;
        float4 v = *reinterpret_cast<const float4*>(&X[((long)b * NN + (nw + n_loc)) * 128 + c4]);
        *reinterpret_cast<float4*>(&Xs[w][n_loc * 4 + b][c4]) = v;
    }
    // no barrier: wave reads only Xs[w][...]
    int b = lane >> 4, h = lane & 15;
    float acc[4] = {0.f, 0.f, 0.f, 0.f};
    for (int c0 = 0; c0 < 128; c0 += 32) {
        float wreg[32];
#pragma unroll
        for (int j = 0; j < 32; ++j) wreg[j] = W1[(c0 + j) * 16 + h];
#pragma unroll
        for (int ni = 0; ni < 4; ++ni) {
            int row = ni * 4 + b;
            float a = 0.f;
#pragma unroll
            for (int j8 = 0; j8 < 8; ++j8) {
                float4 xv = *reinterpret_cast<const float4*>(&Xs[w][row][c0 + j8 * 4]);
                a += xv.x * wreg[j8 * 4] + xv.y * wreg[j8 * 4 + 1]
                   + xv.z * wreg[j8 * 4 + 2] + xv.w * wreg[j8 * 4 + 3];
            }
            acc[ni] += a;
        }
    }
#pragma unroll
    for (int ni = 0; ni < 4; ++ni)
        x1g[(long)(nw + ni) * 64 + lane] = f2bf(acc[ni]);
}

// ---------------- scanA: per-block (512 deg) sums ----------------
__global__ __launch_bounds__(256) void scanA(const int* __restrict__ deg0,
                                             const int* __restrict__ deg1,
                                             int* __restrict__ bsum) {
    int which = blockIdx.x >= NBLK;
    const int* deg = which ? deg1 : deg0;
    int blk = blockIdx.x - which * NBLK;
    int base = blk * 512 + threadIdx.x * 2;
    int d0 = base < NN ? deg[base] : 0;
    int d1 = base + 1 < NN ? deg[base + 1] : 0;
    int s = d0 + d1;
#pragma unroll
    for (int off = 1; off < 64; off <<= 1) s += __shfl_xor(s, off, 64);
    __shared__ int ws4[4];
    int lane = threadIdx.x & 63, wv = threadIdx.x >> 6;
    if (lane == 0) ws4[wv] = s;
    __syncthreads();
    if (threadIdx.x == 0) bsum[blockIdx.x] = ws4[0] + ws4[1] + ws4[2] + ws4[3];
}

// ---------------- scanBp: exclusive scan of block sums (blocks 0,1) + prew (block 2) ----------------
__global__ __launch_bounds__(256) void scanBp(int* __restrict__ bsum,
                                              const float* __restrict__ W1_2,
                                              const float* __restrict__ U2,
                                              const float* __restrict__ V2,
                                              float* __restrict__ WU,
                                              float* __restrict__ WV) {
    int t = threadIdx.x;
    if (blockIdx.x == 2) {  // prew: WU = W1_2@U2, WV = W1_2@V2
        for (int i = t; i < 1024; i += 256) {
            int k = i >> 6, j = i & 63;
            float su = 0.f, sv = 0.f;
            for (int m = 0; m < 64; ++m) {
                float wm = W1_2[k * 64 + m];
                su += wm * U2[m * 64 + j];
                sv += wm * V2[m * 64 + j];
            }
            WU[i] = su;
            WV[i] = sv;
        }
        return;
    }
    int seg = blockIdx.x;
    int v = t < NBLK ? bsum[seg * NBLK + t] : 0;
    int x = v;
    int lane = t & 63, wv = t >> 6;
#pragma unroll
    for (int off = 1; off < 64; off <<= 1) {
        int y = __shfl_up(x, off, 64);
        if (lane >= off) x += y;
    }
    __shared__ int wsum[4];
    __shared__ int wpre[4];
    if (lane == 63) wsum[wv] = x;
    __syncthreads();
    if (t == 0) {
        int s = 0;
        for (int i = 0; i < 4; ++i) { wpre[i] = s; s += wsum[i]; }
    }
    __syncthreads();
    if (t < NBLK) bsum[seg * NBLK + t] = wpre[wv] + x - v;  // exclusive
}

// ---------------- scanC: final exclusive scan, write rp ----------------
__global__ __launch_bounds__(256) void scanC(const int* __restrict__ deg0,
                                             const int* __restrict__ deg1,
                                             const int* __restrict__ bsum,
                                             int* __restrict__ rp0, int* __restrict__ rp1) {
    int which = blockIdx.x >= NBLK;
    const int* deg = which ? deg1 : deg0;
    int* rp = which ? rp1 : rp0;
    int blk = blockIdx.x - which * NBLK;
    int base = blk * 512 + threadIdx.x * 2;
    int d0 = base < NN ? deg[base] : 0;
    int d1 = base + 1 < NN ? deg[base + 1] : 0;
    int s = d0 + d1;
    int x = s;
    int lane = threadIdx.x & 63, wv = threadIdx.x >> 6;
#pragma unroll
    for (int off = 1; off < 64; off <<= 1) {
        int y = __shfl_up(x, off, 64);
        if (lane >= off) x += y;
    }
    __shared__ int wsum[4];
    __shared__ int wpre[4];
    if (lane == 63) wsum[wv] = x;
    __syncthreads();
    if (threadIdx.x == 0) {
        int ss = 0;
        for (int i = 0; i < 4; ++i) { wpre[i] = ss; ss += wsum[i]; }
    }
    __syncthreads();
    int excl = bsum[blockIdx.x] + wpre[wv] + x - s;
    if (base < NN)     rp[base] = excl;
    if (base + 1 < NN) rp[base + 1] = excl + d0;
    if (blk == 0 && threadIdx.x == 0) rp[NN] = EE;
}

// ---------------- scat2: atomic-free scatter (slot = rp[dst]+rank[e]), both lists ----------------
__global__ __launch_bounds__(256) void scat2(const int* __restrict__ ei0, const float* __restrict__ ew0,
                                             const int* __restrict__ rank0, const int* __restrict__ rp0,
                                             int2* __restrict__ ecsr0,
                                             const int* __restrict__ ei1, const float* __restrict__ ew1,
                                             const int* __restrict__ rank1, const int* __restrict__ rp1,
                                             int2* __restrict__ ecsr1) {
    if (blockIdx.x == 0 && threadIdx.x < 32) {
        int i = threadIdx.x;
        if (i < 16) ecsr0[EE + i] = make_int2(0, 0);
        else        ecsr1[EE + i - 16] = make_int2(0, 0);
    }
    int which = blockIdx.x >= HBLK;
    const int* ei = which ? ei1 : ei0;
    const float* ew = which ? ew1 : ew0;
    const int* rank = which ? rank1 : rank0;
    const int* rp = which ? rp1 : rp0;
    int2* ecsr = which ? ecsr1 : ecsr0;
    long c = (long)(blockIdx.x - which * HBLK) * 256 + threadIdx.x;
    if (c >= EE / 4) return;
    long i = c * 4;
    int4 dst4 = *reinterpret_cast<const int4*>(&ei[EE + i]);
    int4 src4 = *reinterpret_cast<const int4*>(&ei[i]);
    int4 rk4  = *reinterpret_cast<const int4*>(&rank[i]);
    float4 w4 = *reinterpret_cast<const float4*>(&ew[i]);
    int s0 = rp[dst4.x] + rk4.x;
    int s1 = rp[dst4.y] + rk4.y;
    int s2 = rp[dst4.z] + rk4.z;
    int s3 = rp[dst4.w] + rk4.w;
    // store pre-scaled byte offsets (src*128) for the gather kernels
    ecsr[s0] = make_int2(src4.x << 7, __float_as_int(w4.x));
    ecsr[s1] = make_int2(src4.y << 7, __float_as_int(w4.y));
    ecsr[s2] = make_int2(src4.z << 7, __float_as_int(w4.z));
    ecsr[s3] = make_int2(src4.w << 7, __float_as_int(w4.w));
}

// ---------------- k3: layer1 gather+epilogue -> h1g bf16 (wave per node) ----------------
__global__ __launch_bounds__(256) void k3(const ushort* __restrict__ x1g,
                                          const int2* __restrict__ ecsr0,
                                          const int* __restrict__ rp0,
                                          const float* __restrict__ W2_1,
                                          const float* __restrict__ U1,
                                          const float* __restrict__ V1,
                                          ushort* __restrict__ h1g) {
    __shared__ float x1s[4][64];
    __shared__ float aggs[4][64];
    int t = threadIdx.x;
    int w = t >> 6, lane = t & 63;
    int b = lane >> 4, h = lane & 15;
    // register-hoisted weight columns (L1-resident, coalesced)
    float ureg[16], vreg[16];
#pragma unroll
    for (int k = 0; k < 16; ++k) { ureg[k] = U1[k * 16 + h]; vreg[k] = V1[k * 16 + h]; }
    float w21 = W2_1[h];
    int n = blockIdx.x * 4 + w;
    const char* xb = (const char*)x1g;
    int lb = lane << 1;
    float xr = bf2f(x1g[(long)n * 64 + lane]);
    int start = rp0[n], end = rp0[n + 1];
    float acc = 0.f;
    int e = start;
    int efull = start + ((end - start) & ~15);
    for (; e < efull; e += 16) {  // full chunks: no mask
        int2 r[16];
#pragma unroll
        for (int i = 0; i < 16; ++i) r[i] = ecsr0[e + i];
        float v[16];
#pragma unroll
        for (int i = 0; i < 16; ++i)
            v[i] = bf2f(*(const ushort*)(xb + (uint)r[i].x + lb));
#pragma unroll
        for (int i = 0; i < 16; ++i) acc += __int_as_float(r[i].y) * v[i];
    }
    if (e < end) {  // masked tail (memory-safe via global pad)
        int2 r[16];
#pragma unroll
        for (int i = 0; i < 16; ++i) r[i] = ecsr0[e + i];
        float v[16];
#pragma unroll
        for (int i = 0; i < 16; ++i)
            v[i] = bf2f(*(const ushort*)(xb + (uint)r[i].x + lb));
#pragma unroll
        for (int i = 0; i < 16; ++i) {
            float wm = (e + i < end) ? __int_as_float(r[i].y) : 0.f;
            acc += wm * v[i];
        }
    }
    x1s[w][lane] = xr;
    aggs[w][lane] = acc;
    float av = 0.f, xu = 0.f;
#pragma unroll
    for (int k = 0; k < 16; ++k) {
        av += aggs[w][b * 16 + k] * vreg[k];
        xu += x1s[w][b * 16 + k] * ureg[k];
    }
    float c = fmaxf((float)(end - start), 1.f);
    float a = xu + w21 * av / c;
    float s = a, s2 = a * a;
#pragma unroll
    for (int off = 32; off >= 1; off >>= 1) {
        s += __shfl_xor(s, off, 64);
        s2 += __shfl_xor(s2, off, 64);
    }
    float mean = s * (1.f / 64.f);
    float var = s2 * (1.f / 64.f) - mean * mean;
    float norm = (a - mean) * rsqrtf(var + EPS);
    float hv = xr + fmaxf(norm, 0.f);
    h1g[(long)n * 64 + lane] = f2bf(hv);
}

// ---------------- k5: layer2 gather(h1g)+epilogue -> out (wave per node) ----------------
__global__ __launch_bounds__(256) void k5(const ushort* __restrict__ h1g,
                                          const int2* __restrict__ ecsr1,
                                          const int* __restrict__ rp1,
                                          const float* __restrict__ W2_2,
                                          const float* __restrict__ W1_2,
                                          const float* __restrict__ WU,
                                          const float* __restrict__ WV,
                                          float* __restrict__ out) {
    __shared__ float h1s[4][64];
    __shared__ float aggs[4][64];
    int t = threadIdx.x;
    int w = t >> 6, lane = t & 63;
    // register-hoisted weight columns (L1-resident, coalesced)
    float w12r[16], wur[16], wvr[16];
#pragma unroll
    for (int k = 0; k < 16; ++k) {
        w12r[k] = W1_2[k * 64 + lane];
        wur[k]  = WU[k * 64 + lane];
        wvr[k]  = WV[k * 64 + lane];
    }
    float w22 = W2_2[lane];
    int n = blockIdx.x * 4 + w;
    const char* hb = (const char*)h1g;
    int lb = lane << 1;
    float hv = bf2f(h1g[(long)n * 64 + lane]);
    int start = rp1[n], end = rp1[n + 1];
    float acc = 0.f;
    int e = start;
    int efull = start + ((end - start) & ~15);
    for (; e < efull; e += 16) {  // full chunks: no mask
        int2 r[16];
#pragma unroll
        for (int i = 0; i < 16; ++i) r[i] = ecsr1[e + i];
        float v[16];
#pragma unroll
        for (int i = 0; i < 16; ++i)
            v[i] = bf2f(*(const ushort*)(hb + (uint)r[i].x + lb));
#pragma unroll
        for (int i = 0; i < 16; ++i) acc += __int_as_float(r[i].y) * v[i];
    }
    if (e < end) {  // masked tail
        int2 r[16];
#pragma unroll
        for (int i = 0; i < 16; ++i) r[i] = ecsr1[e + i];
        float v[16];
#pragma unroll
        for (int i = 0; i < 16; ++i)
            v[i] = bf2f(*(const ushort*)(hb + (uint)r[i].x + lb));
#pragma unroll
        for (int i = 0; i < 16; ++i) {
            float wm = (e + i < end) ? __int_as_float(r[i].y) : 0.f;
            acc += wm * v[i];
        }
    }
    h1s[w][lane] = hv;
    aggs[w][lane] = acc;
    float c = fmaxf((float)(end - start), 1.f);
    float x2b[4], ab[4];
    float s = 0.f, s2 = 0.f;
#pragma unroll
    for (int b = 0; b < 4; ++b) {
        float x2 = 0.f, xu = 0.f, av = 0.f;
#pragma unroll
        for (int k = 0; k < 16; ++k) {
            float hk = h1s[w][b * 16 + k];
            float gk = aggs[w][b * 16 + k];
            x2 += hk * w12r[k];
            xu += hk * wur[k];
            av += gk * wvr[k];
        }
        float a = xu + w22 * av / c;
        x2b[b] = x2;
        ab[b] = a;
        s += a;
        s2 += a * a;
    }
#pragma unroll
    for (int off = 32; off >= 1; off >>= 1) {
        s += __shfl_xor(s, off, 64);
        s2 += __shfl_xor(s2, off, 64);
    }
    float mean = s * (1.f / 256.f);
    float var = s2 * (1.f / 256.f) - mean * mean;
    float rs = rsqrtf(var + EPS);
#pragma unroll
    for (int b = 0; b < 4; ++b) {
        float norm = (ab[b] - mean) * rs;
        out[((long)b * NN + n) * 64 + lane] = x2b[b] + fmaxf(norm, 0.f);
    }
}

extern "C" void kernel_launch(void* const* d_in, const int* in_sizes, int n_in,
                              void* d_out, int out_size, void* d_ws, size_t ws_size,
                              hipStream_t stream) {
    const float* X    = (const float*)d_in[0];
    const int*   ei0  = (const int*)d_in[1];
    const float* ew0  = (const float*)d_in[2];
    const int*   ei1  = (const int*)d_in[3];
    const float* ew1  = (const float*)d_in[4];
    const float* W1_1 = (const float*)d_in[8];
    const float* W2_1 = (const float*)d_in[9];
    const float* U1   = (const float*)d_in[10];
    const float* V1   = (const float*)d_in[11];
    const float* W1_2 = (const float*)d_in[12];
    const float* W2_2 = (const float*)d_in[13];
    const float* U2   = (const float*)d_in[14];
    const float* V2   = (const float*)d_in[15];
    float* out = (float*)d_out;
    char* ws = (char*)d_ws;

    const long MB = 1000000L;
    ushort* x1g  = (ushort*)(ws + 0L);            // 12.8 MB
    ushort* h1g  = (ushort*)(ws + 13 * MB);       // 12.8 MB
    int*    deg0 = (int*)(ws + 26 * MB);          // 400 KB
    int*    deg1 = (int*)(ws + 26 * MB + 400000L);// 400 KB
    int*    bsum = (int*)(ws + 26 * MB + 800000L);// 1.6 KB
    int*    rp0  = (int*)(ws + 27 * MB);          // 400 KB + 4
    int*    rp1  = (int*)(ws + 28 * MB);
    int*    rank0 = (int*)(ws + 29 * MB);         // 6.4 MB
    int*    rank1 = (int*)(ws + 36 * MB);         // 6.4 MB
    int2*   ecsr0 = (int2*)(ws + 43 * MB);        // 12.8 MB + 128 B pad
    int2*   ecsr1 = (int2*)(ws + 56 * MB);        // 12.8 MB + 128 B pad
    float*  WU   = (float*)(ws + 69 * MB);        // 4 KB
    float*  WV   = (float*)(ws + 69 * MB + 4096);

    fill0<<<196, 256, 0, stream>>>((float4*)deg0, 800000L / 16);
    k1h<<<6250, 256, 0, stream>>>(X, W1_1, x1g, ei0, ei1, deg0, deg1, rank0, rank1);
    scanA<<<2 * NBLK, 256, 0, stream>>>(deg0, deg1, bsum);
    scanBp<<<3, 256, 0, stream>>>(bsum, W1_2, U2, V2, WU, WV);
    scanC<<<2 * NBLK, 256, 0, stream>>>(deg0, deg1, bsum, rp0, rp1);
    scat2<<<2 * HBLK, 256, 0, stream>>>(ei0, ew0, rank0, rp0, ecsr0, ei1, ew1, rank1, rp1, ecsr1);
    k3<<<25000, 256, 0, stream>>>(x1g, ecsr0, rp0, W2_1, U1, V1, h1g);
    k5<<<25000, 256, 0, stream>>>(h1g, ecsr1, rp1, W2_2, W1_2, WU, WV, out);
}

// Round 11
// 425.712 us; speedup vs baseline: 1.1876x; 1.1876x over previous
//
#include <hip/hip_runtime.h>

#define NN 100000
#define EE 1600000
#define EPS 1e-5f
#define NBLK 196   // ceil(NN/512)
#define HBLK 1563  // ceil(EE/4/256)

typedef __attribute__((ext_vector_type(8))) short short8;
typedef __attribute__((ext_vector_type(4))) float floatx4;
union FragU { uint u[4]; short8 s; };

__device__ __forceinline__ ushort f2bf(float f) {
    uint u = __float_as_uint(f);
    uint r = (u + 0x7FFF + ((u >> 16) & 1)) >> 16;  // RNE
    return (ushort)r;
}
__device__ __forceinline__ float bf2f(ushort u) {
    return __uint_as_float(((uint)u) << 16);
}

// ---------------- prep: zero deg (blocks 0..195), pack W1_1 B-frags (196), pack k3 B (197) ----------------
__global__ __launch_bounds__(256) void prep(float4* __restrict__ degz,
                                            const float* __restrict__ W1_1,
                                            const float* __restrict__ U1,
                                            const float* __restrict__ V1,
                                            const float* __restrict__ W2_1,
                                            ushort* __restrict__ pack1,
                                            ushort* __restrict__ pack3) {
    int t = threadIdx.x;
    if (blockIdx.x == 196) {
        // pack1[(s*64+l)*8+e] = bf16(W1_1[(s*32 + (l>>4)*8 + e)*16 + (l&15)])
        for (int i = t; i < 2048; i += 256) {
            int e = i & 7, l = (i >> 3) & 63, s = i >> 9;
            pack1[i] = f2bf(W1_1[(s * 32 + ((l >> 4) & 3) * 8 + e) * 16 + (l & 15)]);
        }
        return;
    }
    if (blockIdx.x == 197) {
        // pack3[l*8+e]: B=[[U1],[V1*W2_1col]] 32x16: k'=(l>>4)*8+e, h=l&15
        for (int i = t; i < 512; i += 256) {
            int e = i & 7, l = i >> 3;
            int kk = ((l >> 4) & 3) * 8 + e, h = l & 15;
            float v = (kk < 16) ? U1[kk * 16 + h] : V1[(kk - 16) * 16 + h] * W2_1[h];
            pack3[i] = f2bf(v);
        }
        return;
    }
    long i = (long)blockIdx.x * 256 + t;
    long stride = 196L * 256;
    float4 z = make_float4(0.f, 0.f, 0.f, 0.f);
    for (; i < 50000; i += stride) degz[i] = z;  // 800 KB
}

// ---------------- k1h: x1g = bf16(X@W1_1) via MFMA (no LDS) + fused hist/rank ----------------
__global__ __launch_bounds__(256) void k1h(const float* __restrict__ X,
                                           const ushort* __restrict__ pack1,
                                           ushort* __restrict__ x1g,
                                           const int* __restrict__ ei0, const int* __restrict__ ei1,
                                           int* __restrict__ deg0, int* __restrict__ deg1,
                                           int* __restrict__ rank0, int* __restrict__ rank1) {
    long ce = (long)blockIdx.x * 256 + threadIdx.x;
    if (blockIdx.x < HBLK && ce < EE / 4) {
        long i = ce * 4;
        int4 d0 = *reinterpret_cast<const int4*>(&ei0[EE + i]);
        int4 rk;
        rk.x = atomicAdd(&deg0[d0.x], 1);
        rk.y = atomicAdd(&deg0[d0.y], 1);
        rk.z = atomicAdd(&deg0[d0.z], 1);
        rk.w = atomicAdd(&deg0[d0.w], 1);
        *reinterpret_cast<int4*>(&rank0[i]) = rk;
        int4 d1 = *reinterpret_cast<const int4*>(&ei1[EE + i]);
        int4 rk1;
        rk1.x = atomicAdd(&deg1[d1.x], 1);
        rk1.y = atomicAdd(&deg1[d1.y], 1);
        rk1.z = atomicAdd(&deg1[d1.z], 1);
        rk1.w = atomicAdd(&deg1[d1.w], 1);
        *reinterpret_cast<int4*>(&rank1[i]) = rk1;
    }
    int t = threadIdx.x;
    int w = t >> 6, lane = t & 63;
    int nb = blockIdx.x * 16 + w * 4;      // 4 nodes per wave
    int arow = lane & 15;                  // A row: n_loc = arow>>2, b = arow&3
    int q = lane >> 4;                     // k-quadrant
    long xbase = ((long)(arow & 3) * NN + (nb + (arow >> 2))) * 128 + q * 8;
    floatx4 acc = {0.f, 0.f, 0.f, 0.f};
#pragma unroll
    for (int s = 0; s < 4; ++s) {
        float4 xa = *reinterpret_cast<const float4*>(&X[xbase + s * 32]);
        float4 xb = *reinterpret_cast<const float4*>(&X[xbase + s * 32 + 4]);
        FragU a;
        a.u[0] = ((uint)f2bf(xa.y) << 16) | f2bf(xa.x);
        a.u[1] = ((uint)f2bf(xa.w) << 16) | f2bf(xa.z);
        a.u[2] = ((uint)f2bf(xb.y) << 16) | f2bf(xb.x);
        a.u[3] = ((uint)f2bf(xb.w) << 16) | f2bf(xb.z);
        short8 bfrag = *reinterpret_cast<const short8*>(&pack1[(s * 64 + lane) * 8]);
        acc = __builtin_amdgcn_mfma_f32_16x16x32_bf16(a.s, bfrag, acc, 0, 0, 0);
    }
#pragma unroll
    for (int r = 0; r < 4; ++r) {
        int i = q * 4 + r;                 // C row = X row
        x1g[(long)(nb + (i >> 2)) * 64 + (i & 3) * 16 + (lane & 15)] = f2bf(acc[r]);
    }
}

// ---------------- scanA ----------------
__global__ __launch_bounds__(256) void scanA(const int* __restrict__ deg0,
                                             const int* __restrict__ deg1,
                                             int* __restrict__ bsum) {
    int which = blockIdx.x >= NBLK;
    const int* deg = which ? deg1 : deg0;
    int blk = blockIdx.x - which * NBLK;
    int base = blk * 512 + threadIdx.x * 2;
    int d0 = base < NN ? deg[base] : 0;
    int d1 = base + 1 < NN ? deg[base + 1] : 0;
    int s = d0 + d1;
#pragma unroll
    for (int off = 1; off < 64; off <<= 1) s += __shfl_xor(s, off, 64);
    __shared__ int ws4[4];
    int lane = threadIdx.x & 63, wv = threadIdx.x >> 6;
    if (lane == 0) ws4[wv] = s;
    __syncthreads();
    if (threadIdx.x == 0) bsum[blockIdx.x] = ws4[0] + ws4[1] + ws4[2] + ws4[3];
}

// ---------------- scanBp: scan (blocks 0,1) + prew+pack5 (block 2) ----------------
__global__ __launch_bounds__(256) void scanBp(int* __restrict__ bsum,
                                              const float* __restrict__ W1_2,
                                              const float* __restrict__ U2,
                                              const float* __restrict__ V2,
                                              const float* __restrict__ W2_2,
                                              ushort* __restrict__ pack5a,
                                              ushort* __restrict__ pack5b) {
    int t = threadIdx.x;
    if (blockIdx.x == 2) {
        // thread i = (k, j): WU=W1_2@U2, WV'=(W1_2@V2)*W2_2[j]; pack into B-frag order
        for (int i = t; i < 1024; i += 256) {
            int k = i >> 6, j = i & 63;
            float su = 0.f, sv = 0.f;
            for (int m = 0; m < 64; ++m) {
                float wm = W1_2[k * 64 + m];
                su += wm * U2[m * 64 + j];
                sv += wm * V2[m * 64 + j];
            }
            sv *= W2_2[j];
            int jt = j >> 4;
            int l1 = (k >> 3) * 16 + (j & 15);        // row k (0..15)
            int l2 = (2 + (k >> 3)) * 16 + (j & 15);  // row k+16 (16..31)
            int e = k & 7;
            pack5a[(jt * 64 + l1) * 8 + e] = f2bf(su);
            pack5a[(jt * 64 + l2) * 8 + e] = f2bf(sv);
            pack5b[(jt * 64 + l1) * 8 + e] = f2bf(W1_2[k * 64 + j]);
            pack5b[(jt * 64 + l2) * 8 + e] = 0;
        }
        return;
    }
    int seg = blockIdx.x;
    int v = t < NBLK ? bsum[seg * NBLK + t] : 0;
    int x = v;
    int lane = t & 63, wv = t >> 6;
#pragma unroll
    for (int off = 1; off < 64; off <<= 1) {
        int y = __shfl_up(x, off, 64);
        if (lane >= off) x += y;
    }
    __shared__ int wsum[4];
    __shared__ int wpre[4];
    if (lane == 63) wsum[wv] = x;
    __syncthreads();
    if (t == 0) {
        int s = 0;
        for (int i = 0; i < 4; ++i) { wpre[i] = s; s += wsum[i]; }
    }
    __syncthreads();
    if (t < NBLK) bsum[seg * NBLK + t] = wpre[wv] + x - v;
}

// ---------------- scanC ----------------
__global__ __launch_bounds__(256) void scanC(const int* __restrict__ deg0,
                                             const int* __restrict__ deg1,
                                             const int* __restrict__ bsum,
                                             int* __restrict__ rp0, int* __restrict__ rp1) {
    int which = blockIdx.x >= NBLK;
    const int* deg = which ? deg1 : deg0;
    int* rp = which ? rp1 : rp0;
    int blk = blockIdx.x - which * NBLK;
    int base = blk * 512 + threadIdx.x * 2;
    int d0 = base < NN ? deg[base] : 0;
    int d1 = base + 1 < NN ? deg[base + 1] : 0;
    int s = d0 + d1;
    int x = s;
    int lane = threadIdx.x & 63, wv = threadIdx.x >> 6;
#pragma unroll
    for (int off = 1; off < 64; off <<= 1) {
        int y = __shfl_up(x, off, 64);
        if (lane >= off) x += y;
    }
    __shared__ int wsum[4];
    __shared__ int wpre[4];
    if (lane == 63) wsum[wv] = x;
    __syncthreads();
    if (threadIdx.x == 0) {
        int ss = 0;
        for (int i = 0; i < 4; ++i) { wpre[i] = ss; ss += wsum[i]; }
    }
    __syncthreads();
    int excl = bsum[blockIdx.x] + wpre[wv] + x - s;
    if (base < NN)     rp[base] = excl;
    if (base + 1 < NN) rp[base + 1] = excl + d0;
    if (blk == 0 && threadIdx.x == 0) rp[NN] = EE;
}

// ---------------- scat2: atomic-free scatter ----------------
__global__ __launch_bounds__(256) void scat2(const int* __restrict__ ei0, const float* __restrict__ ew0,
                                             const int* __restrict__ rank0, const int* __restrict__ rp0,
                                             int2* __restrict__ ecsr0,
                                             const int* __restrict__ ei1, const float* __restrict__ ew1,
                                             const int* __restrict__ rank1, const int* __restrict__ rp1,
                                             int2* __restrict__ ecsr1) {
    if (blockIdx.x == 0 && threadIdx.x < 32) {
        int i = threadIdx.x;
        if (i < 16) ecsr0[EE + i] = make_int2(0, 0);
        else        ecsr1[EE + i - 16] = make_int2(0, 0);
    }
    int which = blockIdx.x >= HBLK;
    const int* ei = which ? ei1 : ei0;
    const float* ew = which ? ew1 : ew0;
    const int* rank = which ? rank1 : rank0;
    const int* rp = which ? rp1 : rp0;
    int2* ecsr = which ? ecsr1 : ecsr0;
    long c = (long)(blockIdx.x - which * HBLK) * 256 + threadIdx.x;
    if (c >= EE / 4) return;
    long i = c * 4;
    int4 dst4 = *reinterpret_cast<const int4*>(&ei[EE + i]);
    int4 src4 = *reinterpret_cast<const int4*>(&ei[i]);
    int4 rk4  = *reinterpret_cast<const int4*>(&rank[i]);
    float4 w4 = *reinterpret_cast<const float4*>(&ew[i]);
    int s0 = rp[dst4.x] + rk4.x;
    int s1 = rp[dst4.y] + rk4.y;
    int s2 = rp[dst4.z] + rk4.z;
    int s3 = rp[dst4.w] + rk4.w;
    ecsr[s0] = make_int2(src4.x << 7, __float_as_int(w4.x));
    ecsr[s1] = make_int2(src4.y << 7, __float_as_int(w4.y));
    ecsr[s2] = make_int2(src4.z << 7, __float_as_int(w4.z));
    ecsr[s3] = make_int2(src4.w << 7, __float_as_int(w4.w));
}

// ---------------- k3: gather + MFMA epilogue -> h1g (4 nodes/wave) ----------------
__global__ __launch_bounds__(256) void k3(const ushort* __restrict__ x1g,
                                          const int2* __restrict__ ecsr0,
                                          const int* __restrict__ rp0,
                                          const ushort* __restrict__ pack3,
                                          ushort* __restrict__ h1g) {
    __shared__ ushort xg[4][16][40];  // [wave][row][32 bf16 + pad], 80B rows
    int t = threadIdx.x;
    int w = t >> 6, lane = t & 63;
    int b = lane >> 4;
    int nb = blockIdx.x * 16 + w * 4;
    const char* xb = (const char*)x1g;
    int lb = lane << 1;
    for (int nl = 0; nl < 4; ++nl) {
        int n = nb + nl;
        ushort xr16 = x1g[(long)n * 64 + lane];
        int start = rp0[n], end = rp0[n + 1];
        float acc = 0.f;
        int e = start;
        int efull = start + ((end - start) & ~15);
        for (; e < efull; e += 16) {
            int2 r[16];
#pragma unroll
            for (int i = 0; i < 16; ++i) r[i] = ecsr0[e + i];
            float v[16];
#pragma unroll
            for (int i = 0; i < 16; ++i)
                v[i] = bf2f(*(const ushort*)(xb + (uint)r[i].x + lb));
#pragma unroll
            for (int i = 0; i < 16; ++i) acc += __int_as_float(r[i].y) * v[i];
        }
        if (e < end) {
            int2 r[16];
#pragma unroll
            for (int i = 0; i < 16; ++i) r[i] = ecsr0[e + i];
            float v[16];
#pragma unroll
            for (int i = 0; i < 16; ++i)
                v[i] = bf2f(*(const ushort*)(xb + (uint)r[i].x + lb));
#pragma unroll
            for (int i = 0; i < 16; ++i) {
                float wm = (e + i < end) ? __int_as_float(r[i].y) : 0.f;
                acc += wm * v[i];
            }
        }
        float invc = 1.f / fmaxf((float)(end - start), 1.f);
        xg[w][nl * 4 + b][lane & 15] = xr16;
        xg[w][nl * 4 + b][16 + (lane & 15)] = f2bf(acc * invc);
    }
    // A-frag: row = lane&15, k = (lane>>4)*8+e over [x|g/c]
    short8 afrag = *reinterpret_cast<const short8*>(&xg[w][lane & 15][(lane >> 4) * 8]);
    short8 bfrag = *reinterpret_cast<const short8*>(&pack3[lane * 8]);
    floatx4 a4 = {0.f, 0.f, 0.f, 0.f};
    a4 = __builtin_amdgcn_mfma_f32_16x16x32_bf16(afrag, bfrag, a4, 0, 0, 0);
    // a4[r] = a[node=lane>>4][b=r][h=lane&15]
    float s = 0.f, s2 = 0.f;
#pragma unroll
    for (int r = 0; r < 4; ++r) { s += a4[r]; s2 += a4[r] * a4[r]; }
#pragma unroll
    for (int off = 1; off <= 8; off <<= 1) {
        s += __shfl_xor(s, off, 64);
        s2 += __shfl_xor(s2, off, 64);
    }
    float mean = s * (1.f / 64.f);
    float var = s2 * (1.f / 64.f) - mean * mean;
    float rs = rsqrtf(var + EPS);
    int node = lane >> 4;
#pragma unroll
    for (int r = 0; r < 4; ++r) {
        float xv = bf2f(xg[w][node * 4 + r][lane & 15]);
        float hv = xv + fmaxf((a4[r] - mean) * rs, 0.f);
        h1g[(long)(nb + node) * 64 + r * 16 + (lane & 15)] = f2bf(hv);
    }
}

// ---------------- k5: gather + dual-MFMA epilogue -> out (4 nodes/wave) ----------------
__global__ __launch_bounds__(256) void k5(const ushort* __restrict__ h1g,
                                          const int2* __restrict__ ecsr1,
                                          const int* __restrict__ rp1,
                                          const ushort* __restrict__ pack5a,
                                          const ushort* __restrict__ pack5b,
                                          float* __restrict__ out) {
    __shared__ ushort hg[4][16][40];
    int t = threadIdx.x;
    int w = t >> 6, lane = t & 63;
    int b = lane >> 4;
    int nb = blockIdx.x * 16 + w * 4;
    const char* hb = (const char*)h1g;
    int lb = lane << 1;
    for (int nl = 0; nl < 4; ++nl) {
        int n = nb + nl;
        ushort hv16 = h1g[(long)n * 64 + lane];
        int start = rp1[n], end = rp1[n + 1];
        float acc = 0.f;
        int e = start;
        int efull = start + ((end - start) & ~15);
        for (; e < efull; e += 16) {
            int2 r[16];
#pragma unroll
            for (int i = 0; i < 16; ++i) r[i] = ecsr1[e + i];
            float v[16];
#pragma unroll
            for (int i = 0; i < 16; ++i)
                v[i] = bf2f(*(const ushort*)(hb + (uint)r[i].x + lb));
#pragma unroll
            for (int i = 0; i < 16; ++i) acc += __int_as_float(r[i].y) * v[i];
        }
        if (e < end) {
            int2 r[16];
#pragma unroll
            for (int i = 0; i < 16; ++i) r[i] = ecsr1[e + i];
            float v[16];
#pragma unroll
            for (int i = 0; i < 16; ++i)
                v[i] = bf2f(*(const ushort*)(hb + (uint)r[i].x + lb));
#pragma unroll
            for (int i = 0; i < 16; ++i) {
                float wm = (e + i < end) ? __int_as_float(r[i].y) : 0.f;
                acc += wm * v[i];
            }
        }
        float invc = 1.f / fmaxf((float)(end - start), 1.f);
        hg[w][nl * 4 + b][lane & 15] = hv16;
        hg[w][nl * 4 + b][16 + (lane & 15)] = f2bf(acc * invc);
    }
    short8 afrag = *reinterpret_cast<const short8*>(&hg[w][lane & 15][(lane >> 4) * 8]);
    floatx4 c1[4], c2[4];
#pragma unroll
    for (int jt = 0; jt < 4; ++jt) {
        short8 b1 = *reinterpret_cast<const short8*>(&pack5a[(jt * 64 + lane) * 8]);
        short8 b2 = *reinterpret_cast<const short8*>(&pack5b[(jt * 64 + lane) * 8]);
        floatx4 z = {0.f, 0.f, 0.f, 0.f};
        c1[jt] = __builtin_amdgcn_mfma_f32_16x16x32_bf16(afrag, b1, z, 0, 0, 0);
        c2[jt] = __builtin_amdgcn_mfma_f32_16x16x32_bf16(afrag, b2, z, 0, 0, 0);
    }
    // c1[jt][r] = a_pre[node=lane>>4][b=r][j=jt*16+(lane&15)]; c2 = x2
    float s = 0.f, s2 = 0.f;
#pragma unroll
    for (int jt = 0; jt < 4; ++jt)
#pragma unroll
        for (int r = 0; r < 4; ++r) { float a = c1[jt][r]; s += a; s2 += a * a; }
#pragma unroll
    for (int off = 1; off <= 8; off <<= 1) {
        s += __shfl_xor(s, off, 64);
        s2 += __shfl_xor(s2, off, 64);
    }
    float mean = s * (1.f / 256.f);
    float var = s2 * (1.f / 256.f) - mean * mean;
    float rs = rsqrtf(var + EPS);
    int node = lane >> 4;
    long n = nb + node;
#pragma unroll
    for (int r = 0; r < 4; ++r)
#pragma unroll
        for (int jt = 0; jt < 4; ++jt) {
            float norm = (c1[jt][r] - mean) * rs;
            out[((long)r * NN + n) * 64 + jt * 16 + (lane & 15)] = c2[jt][r] + fmaxf(norm, 0.f);
        }
}

extern "C" void kernel_launch(void* const* d_in, const int* in_sizes, int n_in,
                              void* d_out, int out_size, void* d_ws, size_t ws_size,
                              hipStream_t stream) {
    const float* X    = (const float*)d_in[0];
    const int*   ei0  = (const int*)d_in[1];
    const float* ew0  = (const float*)d_in[2];
    const int*   ei1  = (const int*)d_in[3];
    const float* ew1  = (const float*)d_in[4];
    const float* W1_1 = (const float*)d_in[8];
    const float* W2_1 = (const float*)d_in[9];
    const float* U1   = (const float*)d_in[10];
    const float* V1   = (const float*)d_in[11];
    const float* W1_2 = (const float*)d_in[12];
    const float* W2_2 = (const float*)d_in[13];
    const float* U2   = (const float*)d_in[14];
    const float* V2   = (const float*)d_in[15];
    float* out = (float*)d_out;
    char* ws = (char*)d_ws;

    const long MB = 1000000L;
    ushort* x1g  = (ushort*)(ws + 0L);            // 12.8 MB
    ushort* h1g  = (ushort*)(ws + 13 * MB);       // 12.8 MB
    int*    deg0 = (int*)(ws + 26 * MB);          // 400 KB
    int*    deg1 = (int*)(ws + 26 * MB + 400000L);// 400 KB
    int*    bsum = (int*)(ws + 26 * MB + 800000L);// 1.6 KB
    int*    rp0  = (int*)(ws + 27 * MB);          // 400 KB + 4
    int*    rp1  = (int*)(ws + 28 * MB);
    int*    rank0 = (int*)(ws + 29 * MB);         // 6.4 MB
    int*    rank1 = (int*)(ws + 36 * MB);         // 6.4 MB
    int2*   ecsr0 = (int2*)(ws + 43 * MB);        // 12.8 MB + 128 B pad
    int2*   ecsr1 = (int2*)(ws + 56 * MB);        // 12.8 MB + 128 B pad
    ushort* pack1  = (ushort*)(ws + 69 * MB);            // 4 KB
    ushort* pack3  = (ushort*)(ws + 69 * MB + 8192);     // 1 KB
    ushort* pack5a = (ushort*)(ws + 69 * MB + 16384);    // 4 KB
    ushort* pack5b = (ushort*)(ws + 69 * MB + 24576);    // 4 KB

    prep<<<198, 256, 0, stream>>>((float4*)deg0, W1_1, U1, V1, W2_1, pack1, pack3);
    k1h<<<6250, 256, 0, stream>>>(X, pack1, x1g, ei0, ei1, deg0, deg1, rank0, rank1);
    scanA<<<2 * NBLK, 256, 0, stream>>>(deg0, deg1, bsum);
    scanBp<<<3, 256, 0, stream>>>(bsum, W1_2, U2, V2, W2_2, pack5a, pack5b);
    scanC<<<2 * NBLK, 256, 0, stream>>>(deg0, deg1, bsum, rp0, rp1);
    scat2<<<2 * HBLK, 256, 0, stream>>>(ei0, ew0, rank0, rp0, ecsr0, ei1, ew1, rank1, rp1, ecsr1);
    k3<<<6250, 256, 0, stream>>>(x1g, ecsr0, rp0, pack3, h1g);
    k5<<<6250, 256, 0, stream>>>(h1g, ecsr1, rp1, pack5a, pack5b, out);
}

// Round 12
// 347.493 us; speedup vs baseline: 1.4549x; 1.2251x over previous
//
#include <hip/hip_runtime.h>

#define NN 100000
#define EE 1600000
#define EPS 1e-5f
#define NBUK 391   // ceil(NN/256) 256-node buckets
#define NB1 782    // ceil(EE/2048) edge-blocks per list

typedef __attribute__((ext_vector_type(8))) short short8;
typedef __attribute__((ext_vector_type(4))) float floatx4;
union FragU { uint u[4]; short8 s; };

__device__ __forceinline__ ushort f2bf(float f) {
    uint u = __float_as_uint(f);
    uint r = (u + 0x7FFF + ((u >> 16) & 1)) >> 16;  // RNE
    return (ushort)r;
}
__device__ __forceinline__ float bf2f(ushort u) {
    return __uint_as_float(((uint)u) << 16);
}

// ---------------- prep: pack W1_1 B-frags (block 0), pack k3 B (block 1) ----------------
__global__ __launch_bounds__(256) void prep(const float* __restrict__ W1_1,
                                            const float* __restrict__ U1,
                                            const float* __restrict__ V1,
                                            const float* __restrict__ W2_1,
                                            ushort* __restrict__ pack1,
                                            ushort* __restrict__ pack3) {
    int t = threadIdx.x;
    if (blockIdx.x == 0) {
        for (int i = t; i < 2048; i += 256) {
            int e = i & 7, l = (i >> 3) & 63, s = i >> 9;
            pack1[i] = f2bf(W1_1[(s * 32 + ((l >> 4) & 3) * 8 + e) * 16 + (l & 15)]);
        }
    } else {
        for (int i = t; i < 512; i += 256) {
            int e = i & 7, l = i >> 3;
            int kk = ((l >> 4) & 3) * 8 + e, h = l & 15;
            float v = (kk < 16) ? U1[kk * 16 + h] : V1[(kk - 16) * 16 + h] * W2_1[h];
            pack3[i] = f2bf(v);
        }
    }
}

// ---------------- k1: x1g = bf16(X@W1_1) via MFMA, LDS-staged coalesced X ----------------
__global__ __launch_bounds__(256) void k1(const float* __restrict__ X,
                                          const ushort* __restrict__ pack1,
                                          ushort* __restrict__ x1g) {
    __shared__ __align__(16) float Xs[64][132];
    int t = threadIdx.x;
    int w = t >> 6, lane = t & 63;
    int nb = blockIdx.x * 16;
#pragma unroll
    for (int i = 0; i < 8; ++i) {
        int flat = i * 256 + t;
        int n_loc = flat >> 7;
        int b = (flat >> 5) & 3;
        int c4 = (flat & 31) << 2;
        float4 v = *reinterpret_cast<const float4*>(&X[((long)b * NN + (nb + n_loc)) * 128 + c4]);
        *reinterpret_cast<float4*>(&Xs[n_loc * 4 + b][c4]) = v;
    }
    __syncthreads();
    int arow = lane & 15, q = lane >> 4;
    floatx4 acc = {0.f, 0.f, 0.f, 0.f};
#pragma unroll
    for (int s = 0; s < 4; ++s) {
        const float* xp = &Xs[w * 16 + arow][s * 32 + q * 8];
        float4 xa = *reinterpret_cast<const float4*>(xp);
        float4 xb = *reinterpret_cast<const float4*>(xp + 4);
        FragU a;
        a.u[0] = ((uint)f2bf(xa.y) << 16) | f2bf(xa.x);
        a.u[1] = ((uint)f2bf(xa.w) << 16) | f2bf(xa.z);
        a.u[2] = ((uint)f2bf(xb.y) << 16) | f2bf(xb.x);
        a.u[3] = ((uint)f2bf(xb.w) << 16) | f2bf(xb.z);
        short8 bfrag = *reinterpret_cast<const short8*>(&pack1[(s * 64 + lane) * 8]);
        acc = __builtin_amdgcn_mfma_f32_16x16x32_bf16(a.s, bfrag, acc, 0, 0, 0);
    }
    int nw = nb + w * 4;
#pragma unroll
    for (int r = 0; r < 4; ++r) {
        int i = q * 4 + r;
        x1g[(long)(nw + (i >> 2)) * 64 + (i & 3) * 16 + (lane & 15)] = f2bf(acc[r]);
    }
}

// ---------------- passA: per-block LDS bucket histogram -> bh[l][h][b] ----------------
__global__ __launch_bounds__(256) void passA(const int* __restrict__ ei0,
                                             const int* __restrict__ ei1,
                                             int* __restrict__ bh) {
    int l = blockIdx.x >= NB1;
    int b = blockIdx.x - l * NB1;
    const int* dst = (l ? ei1 : ei0) + EE;
    __shared__ int hist[NBUK];
    int t = threadIdx.x;
    for (int i = t; i < NBUK; i += 256) hist[i] = 0;
    __syncthreads();
    long base = (long)b * 2048;
#pragma unroll
    for (int k = 0; k < 8; ++k) {
        long i = base + k * 256 + t;
        if (i < EE) atomicAdd(&hist[dst[i] >> 8], 1);
    }
    __syncthreads();
    int* bhl = bh + (long)l * NBUK * NB1;
    for (int h = t; h < NBUK; h += 256) bhl[h * NB1 + b] = hist[h];
}

// ---------------- passB: per-bucket exclusive scan over blocks -> cursors + colsum ----------------
__global__ __launch_bounds__(256) void passB(int* __restrict__ bh, int* __restrict__ colsum) {
    int l = blockIdx.x >= NBUK;
    int h = blockIdx.x - l * NBUK;
    int* row = bh + ((long)l * NBUK + h) * NB1;
    int t = threadIdx.x;
    int v[4];
    int s = 0;
    int b0 = t * 4;
#pragma unroll
    for (int j = 0; j < 4; ++j) {
        int b = b0 + j;
        int x = (b < NB1) ? row[b] : 0;
        v[j] = x;
        s += x;
    }
    int lane = t & 63, wv = t >> 6;
    int x = s;
#pragma unroll
    for (int off = 1; off < 64; off <<= 1) {
        int y = __shfl_up(x, off, 64);
        if (lane >= off) x += y;
    }
    __shared__ int wsum[4], wpre[4];
    if (lane == 63) wsum[wv] = x;
    __syncthreads();
    if (t == 0) {
        int ss = 0;
        for (int i = 0; i < 4; ++i) { wpre[i] = ss; ss += wsum[i]; }
    }
    __syncthreads();
    int run = wpre[wv] + x - s;
#pragma unroll
    for (int j = 0; j < 4; ++j) {
        int b = b0 + j;
        if (b < NB1) row[b] = run;
        run += v[j];
    }
    if (t == 255) colsum[l * NBUK + h] = run;
}

// ---------------- gbscan: bucket offsets (blocks 0,1) + pack5/sentinels/rp-ends (block 2) ----------------
__global__ __launch_bounds__(256) void gbscan(const int* __restrict__ colsum, int* __restrict__ gb,
                                              const float* __restrict__ W1_2,
                                              const float* __restrict__ U2,
                                              const float* __restrict__ V2,
                                              const float* __restrict__ W2_2,
                                              ushort* __restrict__ pack5a,
                                              ushort* __restrict__ pack5b,
                                              int2* __restrict__ ecsr0, int2* __restrict__ ecsr1,
                                              int* __restrict__ rp0, int* __restrict__ rp1) {
    int t = threadIdx.x;
    if (blockIdx.x == 2) {
        for (int i = t; i < 1024; i += 256) {
            int k = i >> 6, j = i & 63;
            float su = 0.f, sv = 0.f;
            for (int m = 0; m < 64; ++m) {
                float wm = W1_2[k * 64 + m];
                su += wm * U2[m * 64 + j];
                sv += wm * V2[m * 64 + j];
            }
            sv *= W2_2[j];
            int jt = j >> 4;
            int l1 = (k >> 3) * 16 + (j & 15);
            int l2 = (2 + (k >> 3)) * 16 + (j & 15);
            int e = k & 7;
            pack5a[(jt * 64 + l1) * 8 + e] = f2bf(su);
            pack5a[(jt * 64 + l2) * 8 + e] = f2bf(sv);
            pack5b[(jt * 64 + l1) * 8 + e] = f2bf(W1_2[k * 64 + j]);
            pack5b[(jt * 64 + l2) * 8 + e] = 0;
        }
        if (t < 16) { ecsr0[EE + t] = make_int2(0, 0); ecsr1[EE + t] = make_int2(0, 0); }
        if (t == 16) rp0[NN] = EE;
        if (t == 17) rp1[NN] = EE;
        return;
    }
    int l = blockIdx.x;
    const int* cs = colsum + l * NBUK;
    int v[2];
    int s = 0;
#pragma unroll
    for (int j = 0; j < 2; ++j) {
        int i = t * 2 + j;
        int x = (i < NBUK) ? cs[i] : 0;
        v[j] = x;
        s += x;
    }
    int lane = t & 63, wv = t >> 6;
    int x = s;
#pragma unroll
    for (int off = 1; off < 64; off <<= 1) {
        int y = __shfl_up(x, off, 64);
        if (lane >= off) x += y;
    }
    __shared__ int wsum[4], wpre[4];
    if (lane == 63) wsum[wv] = x;
    __syncthreads();
    if (t == 0) {
        int ss = 0;
        for (int i = 0; i < 4; ++i) { wpre[i] = ss; ss += wsum[i]; }
    }
    __syncthreads();
    int run = wpre[wv] + x - s;
    int* g = gb + l * 392;
#pragma unroll
    for (int j = 0; j < 2; ++j) {
        int i = t * 2 + j;
        if (i < NBUK) g[i] = run;
        run += v[j];
    }
    if (t == 255) g[NBUK] = run;  // = EE
}

// ---------------- passC: scatter edges bucket-ordered into tmp (LDS cursors, no global atomics) ----------------
__global__ __launch_bounds__(256) void passC(const int* __restrict__ ei0, const float* __restrict__ ew0,
                                             const int* __restrict__ ei1, const float* __restrict__ ew1,
                                             const int* __restrict__ bh, const int* __restrict__ gb,
                                             int2* __restrict__ tmp) {
    int l = blockIdx.x >= NB1;
    int b = blockIdx.x - l * NB1;
    const int* ei = l ? ei1 : ei0;
    const float* ew = l ? ew1 : ew0;
    const int* dst = ei + EE;
    __shared__ int cur[NBUK];
    int t = threadIdx.x;
    const int* bhl = bh + (long)l * NBUK * NB1;
    const int* gbl = gb + l * 392;
    for (int h = t; h < NBUK; h += 256) cur[h] = gbl[h] + bhl[h * NB1 + b];
    __syncthreads();
    long base = (long)b * 2048;
    int2* tl = tmp + (long)l * EE;
#pragma unroll
    for (int k = 0; k < 8; ++k) {
        long i = base + k * 256 + t;
        if (i < EE) {
            int d = dst[i];
            int slot = atomicAdd(&cur[d >> 8], 1);
            tl[slot] = make_int2(ei[i] | ((d & 255) << 17), __float_as_int(ew[i]));
        }
    }
}

// ---------------- passD: per-bucket finalize -> rp + ecsr (LDS hist/scan/cursors) ----------------
__global__ __launch_bounds__(256) void passD(const int* __restrict__ gb,
                                             const int2* __restrict__ tmp,
                                             int2* __restrict__ ecsr0, int2* __restrict__ ecsr1,
                                             int* __restrict__ rp0, int* __restrict__ rp1) {
    int l = blockIdx.x >= NBUK;
    int h = blockIdx.x - l * NBUK;
    const int* gbl = gb + l * 392;
    int base = gbl[h], size = gbl[h + 1] - base;
    const int2* tl = tmp + (long)l * EE;
    int2* ecsr = l ? ecsr1 : ecsr0;
    int* rp = l ? rp1 : rp0;
    __shared__ int2 stage[6400];
    __shared__ int hist[256];
    __shared__ int wsum[4], wpre[4];
    int t = threadIdx.x;
    hist[t] = 0;
    __syncthreads();
    bool fit = (size <= 6400);
    for (int i = t; i < size; i += 256) {
        int2 r = tl[base + i];
        if (fit) stage[i] = r;
        atomicAdd(&hist[(r.x >> 17) & 255], 1);
    }
    __syncthreads();
    int v = hist[t];
    int lane = t & 63, wv = t >> 6;
    int x = v;
#pragma unroll
    for (int off = 1; off < 64; off <<= 1) {
        int y = __shfl_up(x, off, 64);
        if (lane >= off) x += y;
    }
    if (lane == 63) wsum[wv] = x;
    __syncthreads();
    if (t == 0) {
        int ss = 0;
        for (int i = 0; i < 4; ++i) { wpre[i] = ss; ss += wsum[i]; }
    }
    __syncthreads();
    int excl = wpre[wv] + x - v;
    int node = h * 256 + t;
    if (node < NN) rp[node] = base + excl;
    __syncthreads();
    hist[t] = excl;
    __syncthreads();
    for (int i = t; i < size; i += 256) {
        int2 r = fit ? stage[i] : tl[base + i];
        int L = (r.x >> 17) & 255;
        int slot = base + atomicAdd(&hist[L], 1);
        ecsr[slot] = make_int2((r.x & 0x1FFFF) << 7, r.y);
    }
}

// ---------------- k3: gather + MFMA epilogue -> h1g (4 nodes/wave) ----------------
__global__ __launch_bounds__(256) void k3(const ushort* __restrict__ x1g,
                                          const int2* __restrict__ ecsr0,
                                          const int* __restrict__ rp0,
                                          const ushort* __restrict__ pack3,
                                          ushort* __restrict__ h1g) {
    __shared__ ushort xg[4][16][40];
    int t = threadIdx.x;
    int w = t >> 6, lane = t & 63;
    int b = lane >> 4;
    int nb = blockIdx.x * 16 + w * 4;
    const char* xb = (const char*)x1g;
    int lb = lane << 1;
    for (int nl = 0; nl < 4; ++nl) {
        int n = nb + nl;
        ushort xr16 = x1g[(long)n * 64 + lane];
        int start = rp0[n], end = rp0[n + 1];
        float acc = 0.f;
        int e = start;
        int efull = start + ((end - start) & ~15);
        for (; e < efull; e += 16) {
            int2 r[16];
#pragma unroll
            for (int i = 0; i < 16; ++i) r[i] = ecsr0[e + i];
            float v[16];
#pragma unroll
            for (int i = 0; i < 16; ++i)
                v[i] = bf2f(*(const ushort*)(xb + (uint)r[i].x + lb));
#pragma unroll
            for (int i = 0; i < 16; ++i) acc += __int_as_float(r[i].y) * v[i];
        }
        if (e < end) {
            int2 r[16];
#pragma unroll
            for (int i = 0; i < 16; ++i) r[i] = ecsr0[e + i];
            float v[16];
#pragma unroll
            for (int i = 0; i < 16; ++i)
                v[i] = bf2f(*(const ushort*)(xb + (uint)r[i].x + lb));
#pragma unroll
            for (int i = 0; i < 16; ++i) {
                float wm = (e + i < end) ? __int_as_float(r[i].y) : 0.f;
                acc += wm * v[i];
            }
        }
        float invc = 1.f / fmaxf((float)(end - start), 1.f);
        xg[w][nl * 4 + b][lane & 15] = xr16;
        xg[w][nl * 4 + b][16 + (lane & 15)] = f2bf(acc * invc);
    }
    short8 afrag = *reinterpret_cast<const short8*>(&xg[w][lane & 15][(lane >> 4) * 8]);
    short8 bfrag = *reinterpret_cast<const short8*>(&pack3[lane * 8]);
    floatx4 a4 = {0.f, 0.f, 0.f, 0.f};
    a4 = __builtin_amdgcn_mfma_f32_16x16x32_bf16(afrag, bfrag, a4, 0, 0, 0);
    float s = 0.f, s2 = 0.f;
#pragma unroll
    for (int r = 0; r < 4; ++r) { s += a4[r]; s2 += a4[r] * a4[r]; }
#pragma unroll
    for (int off = 1; off <= 8; off <<= 1) {
        s += __shfl_xor(s, off, 64);
        s2 += __shfl_xor(s2, off, 64);
    }
    float mean = s * (1.f / 64.f);
    float var = s2 * (1.f / 64.f) - mean * mean;
    float rs = rsqrtf(var + EPS);
    int node = lane >> 4;
#pragma unroll
    for (int r = 0; r < 4; ++r) {
        float xv = bf2f(xg[w][node * 4 + r][lane & 15]);
        float hv = xv + fmaxf((a4[r] - mean) * rs, 0.f);
        h1g[(long)(nb + node) * 64 + r * 16 + (lane & 15)] = f2bf(hv);
    }
}

// ---------------- k5: gather + dual-MFMA epilogue -> out (4 nodes/wave) ----------------
__global__ __launch_bounds__(256) void k5(const ushort* __restrict__ h1g,
                                          const int2* __restrict__ ecsr1,
                                          const int* __restrict__ rp1,
                                          const ushort* __restrict__ pack5a,
                                          const ushort* __restrict__ pack5b,
                                          float* __restrict__ out) {
    __shared__ ushort hg[4][16][40];
    int t = threadIdx.x;
    int w = t >> 6, lane = t & 63;
    int b = lane >> 4;
    int nb = blockIdx.x * 16 + w * 4;
    const char* hb = (const char*)h1g;
    int lb = lane << 1;
    for (int nl = 0; nl < 4; ++nl) {
        int n = nb + nl;
        ushort hv16 = h1g[(long)n * 64 + lane];
        int start = rp1[n], end = rp1[n + 1];
        float acc = 0.f;
        int e = start;
        int efull = start + ((end - start) & ~15);
        for (; e < efull; e += 16) {
            int2 r[16];
#pragma unroll
            for (int i = 0; i < 16; ++i) r[i] = ecsr1[e + i];
            float v[16];
#pragma unroll
            for (int i = 0; i < 16; ++i)
                v[i] = bf2f(*(const ushort*)(hb + (uint)r[i].x + lb));
#pragma unroll
            for (int i = 0; i < 16; ++i) acc += __int_as_float(r[i].y) * v[i];
        }
        if (e < end) {
            int2 r[16];
#pragma unroll
            for (int i = 0; i < 16; ++i) r[i] = ecsr1[e + i];
            float v[16];
#pragma unroll
            for (int i = 0; i < 16; ++i)
                v[i] = bf2f(*(const ushort*)(hb + (uint)r[i].x + lb));
#pragma unroll
            for (int i = 0; i < 16; ++i) {
                float wm = (e + i < end) ? __int_as_float(r[i].y) : 0.f;
                acc += wm * v[i];
            }
        }
        float invc = 1.f / fmaxf((float)(end - start), 1.f);
        hg[w][nl * 4 + b][lane & 15] = hv16;
        hg[w][nl * 4 + b][16 + (lane & 15)] = f2bf(acc * invc);
    }
    short8 afrag = *reinterpret_cast<const short8*>(&hg[w][lane & 15][(lane >> 4) * 8]);
    floatx4 c1[4], c2[4];
#pragma unroll
    for (int jt = 0; jt < 4; ++jt) {
        short8 b1 = *reinterpret_cast<const short8*>(&pack5a[(jt * 64 + lane) * 8]);
        short8 b2 = *reinterpret_cast<const short8*>(&pack5b[(jt * 64 + lane) * 8]);
        floatx4 z = {0.f, 0.f, 0.f, 0.f};
        c1[jt] = __builtin_amdgcn_mfma_f32_16x16x32_bf16(afrag, b1, z, 0, 0, 0);
        c2[jt] = __builtin_amdgcn_mfma_f32_16x16x32_bf16(afrag, b2, z, 0, 0, 0);
    }
    float s = 0.f, s2 = 0.f;
#pragma unroll
    for (int jt = 0; jt < 4; ++jt)
#pragma unroll
        for (int r = 0; r < 4; ++r) { float a = c1[jt][r]; s += a; s2 += a * a; }
#pragma unroll
    for (int off = 1; off <= 8; off <<= 1) {
        s += __shfl_xor(s, off, 64);
        s2 += __shfl_xor(s2, off, 64);
    }
    float mean = s * (1.f / 256.f);
    float var = s2 * (1.f / 256.f) - mean * mean;
    float rs = rsqrtf(var + EPS);
    int node = lane >> 4;
    long n = nb + node;
#pragma unroll
    for (int r = 0; r < 4; ++r)
#pragma unroll
        for (int jt = 0; jt < 4; ++jt) {
            float norm = (c1[jt][r] - mean) * rs;
            out[((long)r * NN + n) * 64 + jt * 16 + (lane & 15)] = c2[jt][r] + fmaxf(norm, 0.f);
        }
}

extern "C" void kernel_launch(void* const* d_in, const int* in_sizes, int n_in,
                              void* d_out, int out_size, void* d_ws, size_t ws_size,
                              hipStream_t stream) {
    const float* X    = (const float*)d_in[0];
    const int*   ei0  = (const int*)d_in[1];
    const float* ew0  = (const float*)d_in[2];
    const int*   ei1  = (const int*)d_in[3];
    const float* ew1  = (const float*)d_in[4];
    const float* W1_1 = (const float*)d_in[8];
    const float* W2_1 = (const float*)d_in[9];
    const float* U1   = (const float*)d_in[10];
    const float* V1   = (const float*)d_in[11];
    const float* W1_2 = (const float*)d_in[12];
    const float* W2_2 = (const float*)d_in[13];
    const float* U2   = (const float*)d_in[14];
    const float* V2   = (const float*)d_in[15];
    float* out = (float*)d_out;
    char* ws = (char*)d_ws;

    const long MB = 1000000L;
    ushort* x1g   = (ushort*)(ws + 0L);             // 12.8 MB
    ushort* h1g   = (ushort*)(ws + 13 * MB);        // 12.8 MB
    int2*   tmp   = (int2*)(ws + 26 * MB);          // 2 x 12.8 MB = 25.6 MB
    int*    bh    = (int*)(ws + 52 * MB);           // 2 x 391 x 782 x 4 = 2.45 MB
    int*    colsum= (int*)(ws + 55 * MB);           // 3.1 KB
    int*    gb    = (int*)(ws + 55 * MB + 4096);    // 3.1 KB
    int*    rp0   = (int*)(ws + 56 * MB);           // 400 KB + 4
    int*    rp1   = (int*)(ws + 57 * MB);
    int2*   ecsr0 = (int2*)(ws + 58 * MB);          // 12.8 MB + 128 B pad
    int2*   ecsr1 = (int2*)(ws + 71 * MB);          // 12.8 MB + 128 B pad
    ushort* pack1  = (ushort*)(ws + 84 * MB);       // 4 KB
    ushort* pack3  = (ushort*)(ws + 84 * MB + 8192);
    ushort* pack5a = (ushort*)(ws + 84 * MB + 16384);
    ushort* pack5b = (ushort*)(ws + 84 * MB + 24576);

    prep<<<2, 256, 0, stream>>>(W1_1, U1, V1, W2_1, pack1, pack3);
    k1<<<6250, 256, 0, stream>>>(X, pack1, x1g);
    passA<<<2 * NB1, 256, 0, stream>>>(ei0, ei1, bh);
    passB<<<2 * NBUK, 256, 0, stream>>>(bh, colsum);
    gbscan<<<3, 256, 0, stream>>>(colsum, gb, W1_2, U2, V2, W2_2, pack5a, pack5b,
                                  ecsr0, ecsr1, rp0, rp1);
    passC<<<2 * NB1, 256, 0, stream>>>(ei0, ew0, ei1, ew1, bh, gb, tmp);
    passD<<<2 * NBUK, 256, 0, stream>>>(gb, tmp, ecsr0, ecsr1, rp0, rp1);
    k3<<<6250, 256, 0, stream>>>(x1g, ecsr0, rp0, pack3, h1g);
    k5<<<6250, 256, 0, stream>>>(h1g, ecsr1, rp1, pack5a, pack5b, out);
}

// Round 13
// 328.149 us; speedup vs baseline: 1.5407x; 1.0590x over previous
//
#include <hip/hip_runtime.h>

#define NN 100000
#define EE 1600000
#define EPS 1e-5f
#define NBUK 391   // ceil(NN/256) 256-node buckets
#define NB1 782    // ceil(EE/2048) edge-blocks per list
#define K1B 6250   // k1 blocks (16 nodes each)

typedef __attribute__((ext_vector_type(8))) short short8;
typedef __attribute__((ext_vector_type(4))) float floatx4;
union FragU { uint u[4]; short8 s; };

__device__ __forceinline__ ushort f2bf(float f) {
    uint u = __float_as_uint(f);
    uint r = (u + 0x7FFF + ((u >> 16) & 1)) >> 16;  // RNE
    return (ushort)r;
}
__device__ __forceinline__ float bf2f(ushort u) {
    return __uint_as_float(((uint)u) << 16);
}

// ---------------- kA: fused k1 (MFMA GEMM) + passA (bucket histogram) ----------------
__global__ __launch_bounds__(256) void kA(const float* __restrict__ X,
                                          const float* __restrict__ W1_1,
                                          ushort* __restrict__ x1g,
                                          const int* __restrict__ ei0,
                                          const int* __restrict__ ei1,
                                          int* __restrict__ bh) {
    __shared__ __align__(16) char smem[64 * 132 * 4 + 4096];
    int t = threadIdx.x;
    if (blockIdx.x >= K1B) {
        // ---- passA part ----
        int bp = blockIdx.x - K1B;
        int l = bp >= NB1;
        int b = bp - l * NB1;
        const int* dst = (l ? ei1 : ei0) + EE;
        int* hist = (int*)smem;
        for (int i = t; i < NBUK; i += 256) hist[i] = 0;
        __syncthreads();
        long base = (long)b * 2048;
#pragma unroll
        for (int k = 0; k < 8; ++k) {
            long i = base + k * 256 + t;
            if (i < EE) atomicAdd(&hist[dst[i] >> 8], 1);
        }
        __syncthreads();
        int* bhl = bh + (long)l * NBUK * NB1;
        for (int h = t; h < NBUK; h += 256) bhl[h * NB1 + b] = hist[h];
        return;
    }
    // ---- k1 part ----
    float (*Xs)[132] = (float(*)[132])smem;
    ushort* Ws = (ushort*)(smem + 64 * 132 * 4);
    int w = t >> 6, lane = t & 63;
    int nb = blockIdx.x * 16;
    for (int i = t; i < 2048; i += 256) {
        int e = i & 7, l = (i >> 3) & 63, s = i >> 9;
        Ws[i] = f2bf(W1_1[(s * 32 + ((l >> 4) & 3) * 8 + e) * 16 + (l & 15)]);
    }
#pragma unroll
    for (int i = 0; i < 8; ++i) {
        int flat = i * 256 + t;
        int n_loc = flat >> 7;
        int b = (flat >> 5) & 3;
        int c4 = (flat & 31) << 2;
        float4 v = *reinterpret_cast<const float4*>(&X[((long)b * NN + (nb + n_loc)) * 128 + c4]);
        *reinterpret_cast<float4*>(&Xs[n_loc * 4 + b][c4]) = v;
    }
    __syncthreads();
    int arow = lane & 15, q = lane >> 4;
    floatx4 acc = {0.f, 0.f, 0.f, 0.f};
#pragma unroll
    for (int s = 0; s < 4; ++s) {
        const float* xp = &Xs[w * 16 + arow][s * 32 + q * 8];
        float4 xa = *reinterpret_cast<const float4*>(xp);
        float4 xb = *reinterpret_cast<const float4*>(xp + 4);
        FragU a;
        a.u[0] = ((uint)f2bf(xa.y) << 16) | f2bf(xa.x);
        a.u[1] = ((uint)f2bf(xa.w) << 16) | f2bf(xa.z);
        a.u[2] = ((uint)f2bf(xb.y) << 16) | f2bf(xb.x);
        a.u[3] = ((uint)f2bf(xb.w) << 16) | f2bf(xb.z);
        short8 bfrag = *reinterpret_cast<const short8*>(&Ws[(s * 64 + lane) * 8]);
        acc = __builtin_amdgcn_mfma_f32_16x16x32_bf16(a.s, bfrag, acc, 0, 0, 0);
    }
    int nw = nb + w * 4;
#pragma unroll
    for (int r = 0; r < 4; ++r) {
        int i = q * 4 + r;
        x1g[(long)(nw + (i >> 2)) * 64 + (i & 3) * 16 + (lane & 15)] = f2bf(acc[r]);
    }
}

// ---------------- passB: per-bucket exclusive scan over blocks -> cursors + colsum ----------------
__global__ __launch_bounds__(256) void passB(int* __restrict__ bh, int* __restrict__ colsum) {
    int l = blockIdx.x >= NBUK;
    int h = blockIdx.x - l * NBUK;
    int* row = bh + ((long)l * NBUK + h) * NB1;
    int t = threadIdx.x;
    int v[4];
    int s = 0;
    int b0 = t * 4;
#pragma unroll
    for (int j = 0; j < 4; ++j) {
        int b = b0 + j;
        int x = (b < NB1) ? row[b] : 0;
        v[j] = x;
        s += x;
    }
    int lane = t & 63, wv = t >> 6;
    int x = s;
#pragma unroll
    for (int off = 1; off < 64; off <<= 1) {
        int y = __shfl_up(x, off, 64);
        if (lane >= off) x += y;
    }
    __shared__ int wsum[4], wpre[4];
    if (lane == 63) wsum[wv] = x;
    __syncthreads();
    if (t == 0) {
        int ss = 0;
        for (int i = 0; i < 4; ++i) { wpre[i] = ss; ss += wsum[i]; }
    }
    __syncthreads();
    int run = wpre[wv] + x - s;
#pragma unroll
    for (int j = 0; j < 4; ++j) {
        int b = b0 + j;
        if (b < NB1) row[b] = run;
        run += v[j];
    }
    if (t == 255) colsum[l * NBUK + h] = run;
}

// ---------------- gbscan: bucket offsets (0,1) + pack5/sentinels/rp-ends (2) + pack3 (3) ----------------
__global__ __launch_bounds__(256) void gbscan(const int* __restrict__ colsum, int* __restrict__ gb,
                                              const float* __restrict__ W1_2,
                                              const float* __restrict__ U2,
                                              const float* __restrict__ V2,
                                              const float* __restrict__ W2_2,
                                              const float* __restrict__ U1,
                                              const float* __restrict__ V1,
                                              const float* __restrict__ W2_1,
                                              ushort* __restrict__ pack5a,
                                              ushort* __restrict__ pack5b,
                                              ushort* __restrict__ pack3,
                                              int2* __restrict__ ecsr0, int2* __restrict__ ecsr1,
                                              int* __restrict__ rp0, int* __restrict__ rp1) {
    int t = threadIdx.x;
    if (blockIdx.x == 3) {
        for (int i = t; i < 512; i += 256) {
            int e = i & 7, l = i >> 3;
            int kk = ((l >> 4) & 3) * 8 + e, h = l & 15;
            float v = (kk < 16) ? U1[kk * 16 + h] : V1[(kk - 16) * 16 + h] * W2_1[h];
            pack3[i] = f2bf(v);
        }
        return;
    }
    if (blockIdx.x == 2) {
        for (int i = t; i < 1024; i += 256) {
            int k = i >> 6, j = i & 63;
            float su = 0.f, sv = 0.f;
            for (int m = 0; m < 64; ++m) {
                float wm = W1_2[k * 64 + m];
                su += wm * U2[m * 64 + j];
                sv += wm * V2[m * 64 + j];
            }
            sv *= W2_2[j];
            int jt = j >> 4;
            int l1 = (k >> 3) * 16 + (j & 15);
            int l2 = (2 + (k >> 3)) * 16 + (j & 15);
            int e = k & 7;
            pack5a[(jt * 64 + l1) * 8 + e] = f2bf(su);
            pack5a[(jt * 64 + l2) * 8 + e] = f2bf(sv);
            pack5b[(jt * 64 + l1) * 8 + e] = f2bf(W1_2[k * 64 + j]);
            pack5b[(jt * 64 + l2) * 8 + e] = 0;
        }
        if (t < 16) { ecsr0[EE + t] = make_int2(0, 0); ecsr1[EE + t] = make_int2(0, 0); }
        if (t == 16) rp0[NN] = EE;
        if (t == 17) rp1[NN] = EE;
        return;
    }
    int l = blockIdx.x;
    const int* cs = colsum + l * NBUK;
    int v[2];
    int s = 0;
#pragma unroll
    for (int j = 0; j < 2; ++j) {
        int i = t * 2 + j;
        int x = (i < NBUK) ? cs[i] : 0;
        v[j] = x;
        s += x;
    }
    int lane = t & 63, wv = t >> 6;
    int x = s;
#pragma unroll
    for (int off = 1; off < 64; off <<= 1) {
        int y = __shfl_up(x, off, 64);
        if (lane >= off) x += y;
    }
    __shared__ int wsum[4], wpre[4];
    if (lane == 63) wsum[wv] = x;
    __syncthreads();
    if (t == 0) {
        int ss = 0;
        for (int i = 0; i < 4; ++i) { wpre[i] = ss; ss += wsum[i]; }
    }
    __syncthreads();
    int run = wpre[wv] + x - s;
    int* g = gb + l * 392;
#pragma unroll
    for (int j = 0; j < 2; ++j) {
        int i = t * 2 + j;
        if (i < NBUK) g[i] = run;
        run += v[j];
    }
    if (t == 255) g[NBUK] = run;  // = EE
}

// ---------------- passC: scatter edges bucket-ordered into tmp (LDS cursors) ----------------
__global__ __launch_bounds__(256) void passC(const int* __restrict__ ei0, const float* __restrict__ ew0,
                                             const int* __restrict__ ei1, const float* __restrict__ ew1,
                                             const int* __restrict__ bh, const int* __restrict__ gb,
                                             int2* __restrict__ tmp) {
    int l = blockIdx.x >= NB1;
    int b = blockIdx.x - l * NB1;
    const int* ei = l ? ei1 : ei0;
    const float* ew = l ? ew1 : ew0;
    const int* dst = ei + EE;
    __shared__ int cur[NBUK];
    int t = threadIdx.x;
    const int* bhl = bh + (long)l * NBUK * NB1;
    const int* gbl = gb + l * 392;
    for (int h = t; h < NBUK; h += 256) cur[h] = gbl[h] + bhl[h * NB1 + b];
    __syncthreads();
    long base = (long)b * 2048;
    int2* tl = tmp + (long)l * EE;
#pragma unroll
    for (int k = 0; k < 8; ++k) {
        long i = base + k * 256 + t;
        if (i < EE) {
            int d = dst[i];
            int slot = atomicAdd(&cur[d >> 8], 1);
            tl[slot] = make_int2(ei[i] | ((d & 255) << 17), __float_as_int(ew[i]));
        }
    }
}

// ---------------- passD: per-bucket finalize -> rp + ecsr ----------------
__global__ __launch_bounds__(256) void passD(const int* __restrict__ gb,
                                             const int2* __restrict__ tmp,
                                             int2* __restrict__ ecsr0, int2* __restrict__ ecsr1,
                                             int* __restrict__ rp0, int* __restrict__ rp1) {
    int l = blockIdx.x >= NBUK;
    int h = blockIdx.x - l * NBUK;
    const int* gbl = gb + l * 392;
    int base = gbl[h], size = gbl[h + 1] - base;
    const int2* tl = tmp + (long)l * EE;
    int2* ecsr = l ? ecsr1 : ecsr0;
    int* rp = l ? rp1 : rp0;
    __shared__ int2 stage[6400];
    __shared__ int hist[256];
    __shared__ int wsum[4], wpre[4];
    int t = threadIdx.x;
    hist[t] = 0;
    __syncthreads();
    bool fit = (size <= 6400);
    for (int i = t; i < size; i += 256) {
        int2 r = tl[base + i];
        if (fit) stage[i] = r;
        atomicAdd(&hist[(r.x >> 17) & 255], 1);
    }
    __syncthreads();
    int v = hist[t];
    int lane = t & 63, wv = t >> 6;
    int x = v;
#pragma unroll
    for (int off = 1; off < 64; off <<= 1) {
        int y = __shfl_up(x, off, 64);
        if (lane >= off) x += y;
    }
    if (lane == 63) wsum[wv] = x;
    __syncthreads();
    if (t == 0) {
        int ss = 0;
        for (int i = 0; i < 4; ++i) { wpre[i] = ss; ss += wsum[i]; }
    }
    __syncthreads();
    int excl = wpre[wv] + x - v;
    int node = h * 256 + t;
    if (node < NN) rp[node] = base + excl;
    __syncthreads();
    hist[t] = excl;
    __syncthreads();
    for (int i = t; i < size; i += 256) {
        int2 r = fit ? stage[i] : tl[base + i];
        int L = (r.x >> 17) & 255;
        int slot = base + atomicAdd(&hist[L], 1);
        ecsr[slot] = make_int2((r.x & 0x1FFFF) << 7, r.y);
    }
}

// ---------------- k3: merged-range gather + MFMA epilogue -> h1g (4 nodes/wave) ----------------
__global__ __launch_bounds__(256) void k3(const ushort* __restrict__ x1g,
                                          const int2* __restrict__ ecsr0,
                                          const int* __restrict__ rp0,
                                          const ushort* __restrict__ pack3,
                                          ushort* __restrict__ h1g) {
    __shared__ ushort xg[4][16][40];
    int t = threadIdx.x;
    int w = t >> 6, lane = t & 63;
    int b = lane >> 4;
    int nb = blockIdx.x * 16 + w * 4;
    const char* xb = (const char*)x1g;
    int lb = lane << 1;
    int s0 = rp0[nb], b1 = rp0[nb + 1], b2 = rp0[nb + 2], b3 = rp0[nb + 3], s4 = rp0[nb + 4];
    float acc0 = 0.f, acc1 = 0.f, acc2 = 0.f, acc3 = 0.f;
    for (int e = s0; e < s4; e += 16) {
        int2 r[16];
#pragma unroll
        for (int i = 0; i < 16; ++i) r[i] = ecsr0[e + i];  // pad-safe
        float v[16];
#pragma unroll
        for (int i = 0; i < 16; ++i)
            v[i] = bf2f(*(const ushort*)(xb + (uint)r[i].x + lb));
#pragma unroll
        for (int i = 0; i < 16; ++i) {
            int gi = e + i;  // wave-uniform
            float wm = (gi < s4) ? __int_as_float(r[i].y) : 0.f;
            float c = wm * v[i];
            acc0 += (gi < b1) ? c : 0.f;
            acc1 += (gi >= b1 && gi < b2) ? c : 0.f;
            acc2 += (gi >= b2 && gi < b3) ? c : 0.f;
            acc3 += (gi >= b3) ? c : 0.f;
        }
    }
    int h = lane & 15;
    xg[w][0 * 4 + b][16 + h] = f2bf(acc0 / fmaxf((float)(b1 - s0), 1.f));
    xg[w][1 * 4 + b][16 + h] = f2bf(acc1 / fmaxf((float)(b2 - b1), 1.f));
    xg[w][2 * 4 + b][16 + h] = f2bf(acc2 / fmaxf((float)(b3 - b2), 1.f));
    xg[w][3 * 4 + b][16 + h] = f2bf(acc3 / fmaxf((float)(s4 - b3), 1.f));
#pragma unroll
    for (int j = 0; j < 4; ++j)
        xg[w][j * 4 + b][h] = x1g[(long)(nb + j) * 64 + lane];
    short8 afrag = *reinterpret_cast<const short8*>(&xg[w][lane & 15][(lane >> 4) * 8]);
    short8 bfrag = *reinterpret_cast<const short8*>(&pack3[lane * 8]);
    floatx4 a4 = {0.f, 0.f, 0.f, 0.f};
    a4 = __builtin_amdgcn_mfma_f32_16x16x32_bf16(afrag, bfrag, a4, 0, 0, 0);
    float s = 0.f, s2 = 0.f;
#pragma unroll
    for (int r = 0; r < 4; ++r) { s += a4[r]; s2 += a4[r] * a4[r]; }
#pragma unroll
    for (int off = 1; off <= 8; off <<= 1) {
        s += __shfl_xor(s, off, 64);
        s2 += __shfl_xor(s2, off, 64);
    }
    float mean = s * (1.f / 64.f);
    float var = s2 * (1.f / 64.f) - mean * mean;
    float rs = rsqrtf(var + EPS);
    int node = lane >> 4;
#pragma unroll
    for (int r = 0; r < 4; ++r) {
        float xv = bf2f(xg[w][node * 4 + r][lane & 15]);
        float hv = xv + fmaxf((a4[r] - mean) * rs, 0.f);
        h1g[(long)(nb + node) * 64 + r * 16 + (lane & 15)] = f2bf(hv);
    }
}

// ---------------- k5: merged-range gather + dual-MFMA epilogue -> out (4 nodes/wave) ----------------
__global__ __launch_bounds__(256) void k5(const ushort* __restrict__ h1g,
                                          const int2* __restrict__ ecsr1,
                                          const int* __restrict__ rp1,
                                          const ushort* __restrict__ pack5a,
                                          const ushort* __restrict__ pack5b,
                                          float* __restrict__ out) {
    __shared__ ushort hg[4][16][40];
    int t = threadIdx.x;
    int w = t >> 6, lane = t & 63;
    int b = lane >> 4;
    int nb = blockIdx.x * 16 + w * 4;
    const char* hb = (const char*)h1g;
    int lb = lane << 1;
    int s0 = rp1[nb], b1 = rp1[nb + 1], b2 = rp1[nb + 2], b3 = rp1[nb + 3], s4 = rp1[nb + 4];
    float acc0 = 0.f, acc1 = 0.f, acc2 = 0.f, acc3 = 0.f;
    for (int e = s0; e < s4; e += 16) {
        int2 r[16];
#pragma unroll
        for (int i = 0; i < 16; ++i) r[i] = ecsr1[e + i];  // pad-safe
        float v[16];
#pragma unroll
        for (int i = 0; i < 16; ++i)
            v[i] = bf2f(*(const ushort*)(hb + (uint)r[i].x + lb));
#pragma unroll
        for (int i = 0; i < 16; ++i) {
            int gi = e + i;  // wave-uniform
            float wm = (gi < s4) ? __int_as_float(r[i].y) : 0.f;
            float c = wm * v[i];
            acc0 += (gi < b1) ? c : 0.f;
            acc1 += (gi >= b1 && gi < b2) ? c : 0.f;
            acc2 += (gi >= b2 && gi < b3) ? c : 0.f;
            acc3 += (gi >= b3) ? c : 0.f;
        }
    }
    int h = lane & 15;
    hg[w][0 * 4 + b][16 + h] = f2bf(acc0 / fmaxf((float)(b1 - s0), 1.f));
    hg[w][1 * 4 + b][16 + h] = f2bf(acc1 / fmaxf((float)(b2 - b1), 1.f));
    hg[w][2 * 4 + b][16 + h] = f2bf(acc2 / fmaxf((float)(b3 - b2), 1.f));
    hg[w][3 * 4 + b][16 + h] = f2bf(acc3 / fmaxf((float)(s4 - b3), 1.f));
#pragma unroll
    for (int j = 0; j < 4; ++j)
        hg[w][j * 4 + b][h] = h1g[(long)(nb + j) * 64 + lane];
    short8 afrag = *reinterpret_cast<const short8*>(&hg[w][lane & 15][(lane >> 4) * 8]);
    floatx4 c1[4], c2[4];
#pragma unroll
    for (int jt = 0; jt < 4; ++jt) {
        short8 bb1 = *reinterpret_cast<const short8*>(&pack5a[(jt * 64 + lane) * 8]);
        short8 bb2 = *reinterpret_cast<const short8*>(&pack5b[(jt * 64 + lane) * 8]);
        floatx4 z = {0.f, 0.f, 0.f, 0.f};
        c1[jt] = __builtin_amdgcn_mfma_f32_16x16x32_bf16(afrag, bb1, z, 0, 0, 0);
        c2[jt] = __builtin_amdgcn_mfma_f32_16x16x32_bf16(afrag, bb2, z, 0, 0, 0);
    }
    float s = 0.f, s2 = 0.f;
#pragma unroll
    for (int jt = 0; jt < 4; ++jt)
#pragma unroll
        for (int r = 0; r < 4; ++r) { float a = c1[jt][r]; s += a; s2 += a * a; }
#pragma unroll
    for (int off = 1; off <= 8; off <<= 1) {
        s += __shfl_xor(s, off, 64);
        s2 += __shfl_xor(s2, off, 64);
    }
    float mean = s * (1.f / 256.f);
    float var = s2 * (1.f / 256.f) - mean * mean;
    float rs = rsqrtf(var + EPS);
    int node = lane >> 4;
    long n = nb + node;
#pragma unroll
    for (int r = 0; r < 4; ++r)
#pragma unroll
        for (int jt = 0; jt < 4; ++jt) {
            float norm = (c1[jt][r] - mean) * rs;
            out[((long)r * NN + n) * 64 + jt * 16 + (lane & 15)] = c2[jt][r] + fmaxf(norm, 0.f);
        }
}

extern "C" void kernel_launch(void* const* d_in, const int* in_sizes, int n_in,
                              void* d_out, int out_size, void* d_ws, size_t ws_size,
                              hipStream_t stream) {
    const float* X    = (const float*)d_in[0];
    const int*   ei0  = (const int*)d_in[1];
    const float* ew0  = (const float*)d_in[2];
    const int*   ei1  = (const int*)d_in[3];
    const float* ew1  = (const float*)d_in[4];
    const float* W1_1 = (const float*)d_in[8];
    const float* W2_1 = (const float*)d_in[9];
    const float* U1   = (const float*)d_in[10];
    const float* V1   = (const float*)d_in[11];
    const float* W1_2 = (const float*)d_in[12];
    const float* W2_2 = (const float*)d_in[13];
    const float* U2   = (const float*)d_in[14];
    const float* V2   = (const float*)d_in[15];
    float* out = (float*)d_out;
    char* ws = (char*)d_ws;

    const long MB = 1000000L;
    ushort* x1g   = (ushort*)(ws + 0L);             // 12.8 MB
    ushort* h1g   = (ushort*)(ws + 13 * MB);        // 12.8 MB
    int2*   tmp   = (int2*)(ws + 26 * MB);          // 2 x 12.8 MB
    int*    bh    = (int*)(ws + 52 * MB);           // 2.45 MB
    int*    colsum= (int*)(ws + 55 * MB);           // 3.1 KB
    int*    gb    = (int*)(ws + 55 * MB + 4096);    // 3.1 KB
    int*    rp0   = (int*)(ws + 56 * MB);           // 400 KB + 4
    int*    rp1   = (int*)(ws + 57 * MB);
    int2*   ecsr0 = (int2*)(ws + 58 * MB);          // 12.8 MB + 128 B pad
    int2*   ecsr1 = (int2*)(ws + 71 * MB);          // 12.8 MB + 128 B pad
    ushort* pack3  = (ushort*)(ws + 84 * MB);       // 1 KB
    ushort* pack5a = (ushort*)(ws + 84 * MB + 8192);
    ushort* pack5b = (ushort*)(ws + 84 * MB + 16384);

    kA<<<K1B + 2 * NB1, 256, 0, stream>>>(X, W1_1, x1g, ei0, ei1, bh);
    passB<<<2 * NBUK, 256, 0, stream>>>(bh, colsum);
    gbscan<<<4, 256, 0, stream>>>(colsum, gb, W1_2, U2, V2, W2_2, U1, V1, W2_1,
                                  pack5a, pack5b, pack3, ecsr0, ecsr1, rp0, rp1);
    passC<<<2 * NB1, 256, 0, stream>>>(ei0, ew0, ei1, ew1, bh, gb, tmp);
    passD<<<2 * NBUK, 256, 0, stream>>>(gb, tmp, ecsr0, ecsr1, rp0, rp1);
    k3<<<K1B, 256, 0, stream>>>(x1g, ecsr0, rp0, pack3, h1g);
    k5<<<K1B, 256, 0, stream>>>(h1g, ecsr1, rp1, pack5a, pack5b, out);
}

// Round 15
// 307.101 us; speedup vs baseline: 1.6463x; 1.0685x over previous
//
#include <hip/hip_runtime.h>

#define NN 100000
#define EE 1600000
#define EPS 1e-5f
#define NBUK 391   // ceil(NN/256) 256-node buckets
#define NB1 782    // ceil(EE/2048) edge-blocks per list
#define K1B 6250   // k1 blocks (16 nodes each)

typedef __attribute__((ext_vector_type(8))) short short8;
typedef __attribute__((ext_vector_type(4))) float floatx4;
union FragU { uint u[4]; short8 s; };

__device__ __forceinline__ ushort f2bf(float f) {
    uint u = __float_as_uint(f);
    uint r = (u + 0x7FFF + ((u >> 16) & 1)) >> 16;  // RNE
    return (ushort)r;
}
__device__ __forceinline__ float bf2f(ushort u) {
    return __uint_as_float(((uint)u) << 16);
}

// block-wide exclusive scan of 256 ints (all 256 threads must call)
__device__ __forceinline__ int blockScanExcl(int v, int* wsum, int* wpre) {
    int t = threadIdx.x, lane = t & 63, wv = t >> 6;
    int x = v;
#pragma unroll
    for (int off = 1; off < 64; off <<= 1) {
        int y = __shfl_up(x, off, 64);
        if (lane >= off) x += y;
    }
    if (lane == 63) wsum[wv] = x;
    __syncthreads();
    if (t == 0) {
        int ss = 0;
        for (int i = 0; i < 4; ++i) { wpre[i] = ss; ss += wsum[i]; }
    }
    __syncthreads();
    return wpre[wv] + x - v;
}

// ---------------- passC body: scatter one 2048-edge block into bucket-ordered tmp ----------------
__device__ __forceinline__ void passC_body(const int* __restrict__ ei, const float* __restrict__ ew,
                                           const int* __restrict__ bhl, const int* __restrict__ gbl,
                                           int2* __restrict__ tl, int b, int* cur) {
    const int* dst = ei + EE;
    int t = threadIdx.x;
    for (int h = t; h < NBUK; h += 256) cur[h] = gbl[h] + bhl[h * NB1 + b];
    __syncthreads();
    long base = (long)b * 2048;
#pragma unroll
    for (int k = 0; k < 8; ++k) {
        long i = base + k * 256 + t;
        if (i < EE) {
            int d = dst[i];
            int slot = atomicAdd(&cur[d >> 8], 1);
            tl[slot] = make_int2(ei[i] | ((d & 255) << 17), __float_as_int(ew[i]));
        }
    }
}

// ---------------- passD body (de-staged): finalize one bucket -> rp + ecsr ----------------
__device__ __forceinline__ void passD_body(const int* __restrict__ gbl, const int2* __restrict__ tl,
                                           int2* __restrict__ ecsr, int* __restrict__ rp,
                                           int h, int* hist, int* wsum, int* wpre) {
    int t = threadIdx.x;
    int base = gbl[h], size = gbl[h + 1] - base;
    hist[t] = 0;
    __syncthreads();
    for (int i = t; i < size; i += 256)
        atomicAdd(&hist[(tl[base + i].x >> 17) & 255], 1);
    __syncthreads();
    int v = hist[t];
    int excl = blockScanExcl(v, wsum, wpre);  // contains barriers ordering read-before-write
    int node = h * 256 + t;
    if (node < NN) rp[node] = base + excl;
    __syncthreads();
    hist[t] = excl;
    __syncthreads();
    for (int i = t; i < size; i += 256) {
        int2 r = tl[base + i];  // L2-hot re-read (33 KB/bucket)
        int L = (r.x >> 17) & 255;
        int slot = base + atomicAdd(&hist[L], 1);
        ecsr[slot] = make_int2((r.x & 0x1FFFF) << 7, r.y);
    }
}

// ---------------- kA: k1 MFMA GEMM ∪ passA histogram ∪ constant packs ----------------
__global__ __launch_bounds__(256) void kA(const float* __restrict__ X,
                                          const float* __restrict__ W1_1,
                                          ushort* __restrict__ x1g,
                                          const int* __restrict__ ei0,
                                          const int* __restrict__ ei1,
                                          int* __restrict__ bh,
                                          const float* __restrict__ W1_2,
                                          const float* __restrict__ U2,
                                          const float* __restrict__ V2,
                                          const float* __restrict__ W2_2,
                                          const float* __restrict__ U1,
                                          const float* __restrict__ V1,
                                          const float* __restrict__ W2_1,
                                          ushort* __restrict__ pack5a,
                                          ushort* __restrict__ pack5b,
                                          ushort* __restrict__ pack3,
                                          int2* __restrict__ ecsr0, int2* __restrict__ ecsr1,
                                          int* __restrict__ rp0, int* __restrict__ rp1) {
    __shared__ __align__(16) char smem[64 * 132 * 4 + 4096];
    int t = threadIdx.x;
    if (blockIdx.x >= K1B + 2 * NB1) {
        if (blockIdx.x == K1B + 2 * NB1) {
            // pack5a/b + sentinels + rp ends
            for (int i = t; i < 1024; i += 256) {
                int k = i >> 6, j = i & 63;
                float su = 0.f, sv = 0.f;
                for (int m = 0; m < 64; ++m) {
                    float wm = W1_2[k * 64 + m];
                    su += wm * U2[m * 64 + j];
                    sv += wm * V2[m * 64 + j];
                }
                sv *= W2_2[j];
                int jt = j >> 4;
                int l1 = (k >> 3) * 16 + (j & 15);
                int l2 = (2 + (k >> 3)) * 16 + (j & 15);
                int e = k & 7;
                pack5a[(jt * 64 + l1) * 8 + e] = f2bf(su);
                pack5a[(jt * 64 + l2) * 8 + e] = f2bf(sv);
                pack5b[(jt * 64 + l1) * 8 + e] = f2bf(W1_2[k * 64 + j]);
                pack5b[(jt * 64 + l2) * 8 + e] = 0;
            }
            if (t < 16) { ecsr0[EE + t] = make_int2(0, 0); ecsr1[EE + t] = make_int2(0, 0); }
            if (t == 16) rp0[NN] = EE;
            if (t == 17) rp1[NN] = EE;
        } else {
            // pack3
            for (int i = t; i < 512; i += 256) {
                int e = i & 7, l = i >> 3;
                int kk = ((l >> 4) & 3) * 8 + e, h = l & 15;
                float v = (kk < 16) ? U1[kk * 16 + h] : V1[(kk - 16) * 16 + h] * W2_1[h];
                pack3[i] = f2bf(v);
            }
        }
        return;
    }
    if (blockIdx.x >= K1B) {
        // ---- passA ----
        int bp = blockIdx.x - K1B;
        int l = bp >= NB1;
        int b = bp - l * NB1;
        const int* dst = (l ? ei1 : ei0) + EE;
        int* hist = (int*)smem;
        for (int i = t; i < NBUK; i += 256) hist[i] = 0;
        __syncthreads();
        long base = (long)b * 2048;
#pragma unroll
        for (int k = 0; k < 8; ++k) {
            long i = base + k * 256 + t;
            if (i < EE) atomicAdd(&hist[dst[i] >> 8], 1);
        }
        __syncthreads();
        int* bhl = bh + (long)l * NBUK * NB1;
        for (int h = t; h < NBUK; h += 256) bhl[h * NB1 + b] = hist[h];
        return;
    }
    // ---- k1 MFMA GEMM ----
    float (*Xs)[132] = (float(*)[132])smem;
    ushort* Ws = (ushort*)(smem + 64 * 132 * 4);
    int w = t >> 6, lane = t & 63;
    int nb = blockIdx.x * 16;
    for (int i = t; i < 2048; i += 256) {
        int e = i & 7, l = (i >> 3) & 63, s = i >> 9;
        Ws[i] = f2bf(W1_1[(s * 32 + ((l >> 4) & 3) * 8 + e) * 16 + (l & 15)]);
    }
#pragma unroll
    for (int i = 0; i < 8; ++i) {
        int flat = i * 256 + t;
        int n_loc = flat >> 7;
        int b = (flat >> 5) & 3;
        int c4 = (flat & 31) << 2;
        float4 v = *reinterpret_cast<const float4*>(&X[((long)b * NN + (nb + n_loc)) * 128 + c4]);
        *reinterpret_cast<float4*>(&Xs[n_loc * 4 + b][c4]) = v;
    }
    __syncthreads();
    int arow = lane & 15, q = lane >> 4;
    floatx4 acc = {0.f, 0.f, 0.f, 0.f};
#pragma unroll
    for (int s = 0; s < 4; ++s) {
        const float* xp = &Xs[w * 16 + arow][s * 32 + q * 8];
        float4 xa = *reinterpret_cast<const float4*>(xp);
        float4 xb = *reinterpret_cast<const float4*>(xp + 4);
        FragU a;
        a.u[0] = ((uint)f2bf(xa.y) << 16) | f2bf(xa.x);
        a.u[1] = ((uint)f2bf(xa.w) << 16) | f2bf(xa.z);
        a.u[2] = ((uint)f2bf(xb.y) << 16) | f2bf(xb.x);
        a.u[3] = ((uint)f2bf(xb.w) << 16) | f2bf(xb.z);
        short8 bfrag = *reinterpret_cast<const short8*>(&Ws[(s * 64 + lane) * 8]);
        acc = __builtin_amdgcn_mfma_f32_16x16x32_bf16(a.s, bfrag, acc, 0, 0, 0);
    }
    int nw = nb + w * 4;
#pragma unroll
    for (int r = 0; r < 4; ++r) {
        int i = q * 4 + r;
        x1g[(long)(nw + (i >> 2)) * 64 + (i & 3) * 16 + (lane & 15)] = f2bf(acc[r]);
    }
}

// ---------------- passB: per-bucket exclusive scan over blocks -> cursors + colsum ----------------
__global__ __launch_bounds__(256) void passB(int* __restrict__ bh, int* __restrict__ colsum) {
    int l = blockIdx.x >= NBUK;
    int h = blockIdx.x - l * NBUK;
    int* row = bh + ((long)l * NBUK + h) * NB1;
    int t = threadIdx.x;
    int v[4];
    int s = 0;
    int b0 = t * 4;
#pragma unroll
    for (int j = 0; j < 4; ++j) {
        int b = b0 + j;
        int x = (b < NB1) ? row[b] : 0;
        v[j] = x;
        s += x;
    }
    __shared__ int wsum[4], wpre[4];
    int run = blockScanExcl(s, wsum, wpre);
#pragma unroll
    for (int j = 0; j < 4; ++j) {
        int b = b0 + j;
        if (b < NB1) row[b] = run;
        run += v[j];
    }
    if (t == 255) colsum[l * NBUK + h] = run;
}

// ---------------- gbscan: bucket offsets per list (2 blocks) ----------------
__global__ __launch_bounds__(256) void gbscan(const int* __restrict__ colsum, int* __restrict__ gb) {
    int l = blockIdx.x;
    int t = threadIdx.x;
    const int* cs = colsum + l * NBUK;
    int v[2];
    int s = 0;
#pragma unroll
    for (int j = 0; j < 2; ++j) {
        int i = t * 2 + j;
        int x = (i < NBUK) ? cs[i] : 0;
        v[j] = x;
        s += x;
    }
    __shared__ int wsum[4], wpre[4];
    int run = blockScanExcl(s, wsum, wpre);
    int* g = gb + l * 392;
#pragma unroll
    for (int j = 0; j < 2; ++j) {
        int i = t * 2 + j;
        if (i < NBUK) g[i] = run;
        run += v[j];
    }
    if (t == 255) g[NBUK] = run;  // = EE
}

// ---------------- passC0: list-0 scatter ----------------
__global__ __launch_bounds__(256) void passC0(const int* __restrict__ ei0, const float* __restrict__ ew0,
                                              const int* __restrict__ bh, const int* __restrict__ gb,
                                              int2* __restrict__ tmp) {
    __shared__ int cur[NBUK];
    passC_body(ei0, ew0, bh, gb, tmp, blockIdx.x, cur);
}

// ---------------- fuseDC: passD(list0) ∪ passC(list1) ----------------
__global__ __launch_bounds__(256) void fuseDC(const int* __restrict__ gb, int2* __restrict__ tmp,
                                              int2* __restrict__ ecsr0, int* __restrict__ rp0,
                                              const int* __restrict__ ei1, const float* __restrict__ ew1,
                                              const int* __restrict__ bh) {
    __shared__ int sh[NBUK];  // union: passD hist(256) / passC cur(NBUK)
    __shared__ int wsum[4], wpre[4];
    if (blockIdx.x < NBUK) {
        passD_body(gb, tmp, ecsr0, rp0, blockIdx.x, sh, wsum, wpre);
    } else {
        passC_body(ei1, ew1, bh + (long)NBUK * NB1, gb + 392, tmp + (long)EE,
                   blockIdx.x - NBUK, sh);
    }
}

// ---------------- k3 body: merged-range gather + MFMA epilogue (4 nodes/wave) ----------------
__device__ __forceinline__ void k3_body(const ushort* __restrict__ x1g,
                                        const int2* __restrict__ ecsr0,
                                        const int* __restrict__ rp0,
                                        const ushort* __restrict__ pack3,
                                        ushort* __restrict__ h1g,
                                        ushort (*xg)[16][40], int blk) {
    int t = threadIdx.x;
    int w = t >> 6, lane = t & 63;
    int b = lane >> 4;
    int nb = blk * 16 + w * 4;
    const char* xb = (const char*)x1g;
    int lb = lane << 1;
    int s0 = rp0[nb], b1 = rp0[nb + 1], b2 = rp0[nb + 2], b3 = rp0[nb + 3], s4 = rp0[nb + 4];
    float acc0 = 0.f, acc1 = 0.f, acc2 = 0.f, acc3 = 0.f;
    for (int e = s0; e < s4; e += 16) {
        int2 r[16];
#pragma unroll
        for (int i = 0; i < 16; ++i) r[i] = ecsr0[e + i];  // pad-safe
        float v[16];
#pragma unroll
        for (int i = 0; i < 16; ++i)
            v[i] = bf2f(*(const ushort*)(xb + (uint)r[i].x + lb));
#pragma unroll
        for (int i = 0; i < 16; ++i) {
            int gi = e + i;  // wave-uniform
            float wm = (gi < s4) ? __int_as_float(r[i].y) : 0.f;
            float c = wm * v[i];
            acc0 += (gi < b1) ? c : 0.f;
            acc1 += (gi >= b1 && gi < b2) ? c : 0.f;
            acc2 += (gi >= b2 && gi < b3) ? c : 0.f;
            acc3 += (gi >= b3) ? c : 0.f;
        }
    }
    int h = lane & 15;
    xg[w][0 * 4 + b][16 + h] = f2bf(acc0 / fmaxf((float)(b1 - s0), 1.f));
    xg[w][1 * 4 + b][16 + h] = f2bf(acc1 / fmaxf((float)(b2 - b1), 1.f));
    xg[w][2 * 4 + b][16 + h] = f2bf(acc2 / fmaxf((float)(b3 - b2), 1.f));
    xg[w][3 * 4 + b][16 + h] = f2bf(acc3 / fmaxf((float)(s4 - b3), 1.f));
#pragma unroll
    for (int j = 0; j < 4; ++j)
        xg[w][j * 4 + b][h] = x1g[(long)(nb + j) * 64 + lane];
    short8 afrag = *reinterpret_cast<const short8*>(&xg[w][lane & 15][(lane >> 4) * 8]);
    short8 bfrag = *reinterpret_cast<const short8*>(&pack3[lane * 8]);
    floatx4 a4 = {0.f, 0.f, 0.f, 0.f};
    a4 = __builtin_amdgcn_mfma_f32_16x16x32_bf16(afrag, bfrag, a4, 0, 0, 0);
    float s = 0.f, s2 = 0.f;
#pragma unroll
    for (int r = 0; r < 4; ++r) { s += a4[r]; s2 += a4[r] * a4[r]; }
#pragma unroll
    for (int off = 1; off <= 8; off <<= 1) {
        s += __shfl_xor(s, off, 64);
        s2 += __shfl_xor(s2, off, 64);
    }
    float mean = s * (1.f / 64.f);
    float var = s2 * (1.f / 64.f) - mean * mean;
    float rs = rsqrtf(var + EPS);
    int node = lane >> 4;
#pragma unroll
    for (int r = 0; r < 4; ++r) {
        float xv = bf2f(xg[w][node * 4 + r][lane & 15]);
        float hv = xv + fmaxf((a4[r] - mean) * rs, 0.f);
        h1g[(long)(nb + node) * 64 + r * 16 + (lane & 15)] = f2bf(hv);
    }
}

// ---------------- fuseKD: k3 ∪ passD(list1) ----------------
__global__ __launch_bounds__(256) void fuseKD(const ushort* __restrict__ x1g,
                                              const int2* __restrict__ ecsr0,
                                              const int* __restrict__ rp0,
                                              const ushort* __restrict__ pack3,
                                              ushort* __restrict__ h1g,
                                              const int* __restrict__ gb,
                                              const int2* __restrict__ tmp,
                                              int2* __restrict__ ecsr1,
                                              int* __restrict__ rp1) {
    __shared__ ushort xg[4][16][40];
    __shared__ int hist[256];
    __shared__ int wsum[4], wpre[4];
    if (blockIdx.x < K1B) {
        k3_body(x1g, ecsr0, rp0, pack3, h1g, xg, blockIdx.x);
    } else {
        passD_body(gb + 392, tmp + (long)EE, ecsr1, rp1, blockIdx.x - K1B, hist, wsum, wpre);
    }
}

// ---------------- k5: merged-range gather + dual-MFMA epilogue -> out (4 nodes/wave) ----------------
__global__ __launch_bounds__(256) void k5(const ushort* __restrict__ h1g,
                                          const int2* __restrict__ ecsr1,
                                          const int* __restrict__ rp1,
                                          const ushort* __restrict__ pack5a,
                                          const ushort* __restrict__ pack5b,
                                          float* __restrict__ out) {
    __shared__ ushort hg[4][16][40];
    int t = threadIdx.x;
    int w = t >> 6, lane = t & 63;
    int b = lane >> 4;
    int nb = blockIdx.x * 16 + w * 4;
    const char* hb = (const char*)h1g;
    int lb = lane << 1;
    int s0 = rp1[nb], b1 = rp1[nb + 1], b2 = rp1[nb + 2], b3 = rp1[nb + 3], s4 = rp1[nb + 4];
    float acc0 = 0.f, acc1 = 0.f, acc2 = 0.f, acc3 = 0.f;
    for (int e = s0; e < s4; e += 16) {
        int2 r[16];
#pragma unroll
        for (int i = 0; i < 16; ++i) r[i] = ecsr1[e + i];  // pad-safe
        float v[16];
#pragma unroll
        for (int i = 0; i < 16; ++i)
            v[i] = bf2f(*(const ushort*)(hb + (uint)r[i].x + lb));
#pragma unroll
        for (int i = 0; i < 16; ++i) {
            int gi = e + i;  // wave-uniform
            float wm = (gi < s4) ? __int_as_float(r[i].y) : 0.f;
            float c = wm * v[i];
            acc0 += (gi < b1) ? c : 0.f;
            acc1 += (gi >= b1 && gi < b2) ? c : 0.f;
            acc2 += (gi >= b2 && gi < b3) ? c : 0.f;
            acc3 += (gi >= b3) ? c : 0.f;
        }
    }
    int h = lane & 15;
    hg[w][0 * 4 + b][16 + h] = f2bf(acc0 / fmaxf((float)(b1 - s0), 1.f));
    hg[w][1 * 4 + b][16 + h] = f2bf(acc1 / fmaxf((float)(b2 - b1), 1.f));
    hg[w][2 * 4 + b][16 + h] = f2bf(acc2 / fmaxf((float)(b3 - b2), 1.f));
    hg[w][3 * 4 + b][16 + h] = f2bf(acc3 / fmaxf((float)(s4 - b3), 1.f));
#pragma unroll
    for (int j = 0; j < 4; ++j)
        hg[w][j * 4 + b][h] = h1g[(long)(nb + j) * 64 + lane];
    short8 afrag = *reinterpret_cast<const short8*>(&hg[w][lane & 15][(lane >> 4) * 8]);
    floatx4 c1[4], c2[4];
#pragma unroll
    for (int jt = 0; jt < 4; ++jt) {
        short8 bb1 = *reinterpret_cast<const short8*>(&pack5a[(jt * 64 + lane) * 8]);
        short8 bb2 = *reinterpret_cast<const short8*>(&pack5b[(jt * 64 + lane) * 8]);
        floatx4 z = {0.f, 0.f, 0.f, 0.f};
        c1[jt] = __builtin_amdgcn_mfma_f32_16x16x32_bf16(afrag, bb1, z, 0, 0, 0);
        c2[jt] = __builtin_amdgcn_mfma_f32_16x16x32_bf16(afrag, bb2, z, 0, 0, 0);
    }
    float s = 0.f, s2 = 0.f;
#pragma unroll
    for (int jt = 0; jt < 4; ++jt)
#pragma unroll
        for (int r = 0; r < 4; ++r) { float a = c1[jt][r]; s += a; s2 += a * a; }
#pragma unroll
    for (int off = 1; off <= 8; off <<= 1) {
        s += __shfl_xor(s, off, 64);
        s2 += __shfl_xor(s2, off, 64);
    }
    float mean = s * (1.f / 256.f);
    float var = s2 * (1.f / 256.f) - mean * mean;
    float rs = rsqrtf(var + EPS);
    int node = lane >> 4;
    long n = nb + node;
#pragma unroll
    for (int r = 0; r < 4; ++r)
#pragma unroll
        for (int jt = 0; jt < 4; ++jt) {
            float norm = (c1[jt][r] - mean) * rs;
            out[((long)r * NN + n) * 64 + jt * 16 + (lane & 15)] = c2[jt][r] + fmaxf(norm, 0.f);
        }
}

extern "C" void kernel_launch(void* const* d_in, const int* in_sizes, int n_in,
                              void* d_out, int out_size, void* d_ws, size_t ws_size,
                              hipStream_t stream) {
    const float* X    = (const float*)d_in[0];
    const int*   ei0  = (const int*)d_in[1];
    const float* ew0  = (const float*)d_in[2];
    const int*   ei1  = (const int*)d_in[3];
    const float* ew1  = (const float*)d_in[4];
    const float* W1_1 = (const float*)d_in[8];
    const float* W2_1 = (const float*)d_in[9];
    const float* U1   = (const float*)d_in[10];
    const float* V1   = (const float*)d_in[11];
    const float* W1_2 = (const float*)d_in[12];
    const float* W2_2 = (const float*)d_in[13];
    const float* U2   = (const float*)d_in[14];
    const float* V2   = (const float*)d_in[15];
    float* out = (float*)d_out;
    char* ws = (char*)d_ws;

    const long MB = 1000000L;
    ushort* x1g   = (ushort*)(ws + 0L);             // 12.8 MB
    ushort* h1g   = (ushort*)(ws + 13 * MB);        // 12.8 MB
    int2*   tmp   = (int2*)(ws + 26 * MB);          // 2 x 12.8 MB
    int*    bh    = (int*)(ws + 52 * MB);           // 2.45 MB
    int*    colsum= (int*)(ws + 55 * MB);           // 3.1 KB
    int*    gb    = (int*)(ws + 55 * MB + 4096);    // 3.1 KB
    int*    rp0   = (int*)(ws + 56 * MB);           // 400 KB + 4
    int*    rp1   = (int*)(ws + 57 * MB);
    int2*   ecsr0 = (int2*)(ws + 58 * MB);          // 12.8 MB + 128 B pad
    int2*   ecsr1 = (int2*)(ws + 71 * MB);          // 12.8 MB + 128 B pad
    ushort* pack3  = (ushort*)(ws + 84 * MB);       // 1 KB
    ushort* pack5a = (ushort*)(ws + 84 * MB + 8192);
    ushort* pack5b = (ushort*)(ws + 84 * MB + 16384);

    kA<<<K1B + 2 * NB1 + 2, 256, 0, stream>>>(X, W1_1, x1g, ei0, ei1, bh,
                                              W1_2, U2, V2, W2_2, U1, V1, W2_1,
                                              pack5a, pack5b, pack3, ecsr0, ecsr1, rp0, rp1);
    passB<<<2 * NBUK, 256, 0, stream>>>(bh, colsum);
    gbscan<<<2, 256, 0, stream>>>(colsum, gb);
    passC0<<<NB1, 256, 0, stream>>>(ei0, ew0, bh, gb, tmp);
    fuseDC<<<NBUK + NB1, 256, 0, stream>>>(gb, tmp, ecsr0, rp0, ei1, ew1, bh);
    fuseKD<<<K1B + NBUK, 256, 0, stream>>>(x1g, ecsr0, rp0, pack3, h1g, gb, tmp, ecsr1, rp1);
    k5<<<K1B, 256, 0, stream>>>(h1g, ecsr1, rp1, pack5a, pack5b, out);
}

// Round 16
// 290.345 us; speedup vs baseline: 1.7413x; 1.0577x over previous
//
#include <hip/hip_runtime.h>

#define NN 100000
#define EE 1600000
#define EPS 1e-5f
#define NBUK 391   // ceil(NN/256) 256-node buckets
#define NB1 782    // ceil(EE/2048) edge-blocks per list
#define K1B 6250   // k1 blocks (16 nodes each)

typedef __attribute__((ext_vector_type(8))) short short8;
typedef __attribute__((ext_vector_type(4))) float floatx4;
union FragU { uint u[4]; short8 s; };

__device__ __forceinline__ ushort f2bf(float f) {
    uint u = __float_as_uint(f);
    uint r = (u + 0x7FFF + ((u >> 16) & 1)) >> 16;  // RNE
    return (ushort)r;
}
__device__ __forceinline__ float bf2f(ushort u) {
    return __uint_as_float(((uint)u) << 16);
}

// block-wide exclusive scan of 256 ints (all 256 threads must call)
__device__ __forceinline__ int blockScanExcl(int v, int* wsum, int* wpre) {
    int t = threadIdx.x, lane = t & 63, wv = t >> 6;
    int x = v;
#pragma unroll
    for (int off = 1; off < 64; off <<= 1) {
        int y = __shfl_up(x, off, 64);
        if (lane >= off) x += y;
    }
    if (lane == 63) wsum[wv] = x;
    __syncthreads();
    if (t == 0) {
        int ss = 0;
        for (int i = 0; i < 4; ++i) { wpre[i] = ss; ss += wsum[i]; }
    }
    __syncthreads();
    return wpre[wv] + x - v;
}

// ---------------- passC body: scatter one 2048-edge block into bucket-ordered tmp ----------------
__device__ __forceinline__ void passC_body(const int* __restrict__ ei, const float* __restrict__ ew,
                                           const int* __restrict__ bhl, const int* __restrict__ gbl,
                                           int2* __restrict__ tl, int b, int* cur) {
    const int* dst = ei + EE;
    int t = threadIdx.x;
    for (int h = t; h < NBUK; h += 256) cur[h] = gbl[h] + bhl[h * NB1 + b];
    __syncthreads();
    long base = (long)b * 2048;
#pragma unroll
    for (int k = 0; k < 8; ++k) {
        long i = base + k * 256 + t;
        if (i < EE) {
            int d = dst[i];
            int slot = atomicAdd(&cur[d >> 8], 1);
            tl[slot] = make_int2(ei[i] | ((d & 255) << 17), __float_as_int(ew[i]));
        }
    }
}

// ---------------- passD body (de-staged): finalize one bucket -> rp + ecsr ----------------
__device__ __forceinline__ void passD_body(const int* __restrict__ gbl, const int2* __restrict__ tl,
                                           int2* __restrict__ ecsr, int* __restrict__ rp,
                                           int h, int* hist, int* wsum, int* wpre) {
    int t = threadIdx.x;
    int base = gbl[h], size = gbl[h + 1] - base;
    hist[t] = 0;
    __syncthreads();
    for (int i = t; i < size; i += 256)
        atomicAdd(&hist[(tl[base + i].x >> 17) & 255], 1);
    __syncthreads();
    int v = hist[t];
    int excl = blockScanExcl(v, wsum, wpre);  // contains barriers ordering read-before-write
    int node = h * 256 + t;
    if (node < NN) rp[node] = base + excl;
    __syncthreads();
    hist[t] = excl;
    __syncthreads();
    for (int i = t; i < size; i += 256) {
        int2 r = tl[base + i];  // L2-hot re-read (33 KB/bucket)
        int L = (r.x >> 17) & 255;
        int slot = base + atomicAdd(&hist[L], 1);
        ecsr[slot] = make_int2((r.x & 0x1FFFF) << 7, r.y);
    }
}

// ---------------- kA: k1 MFMA GEMM ∪ passA histogram ∪ constant packs ----------------
__global__ __launch_bounds__(256) void kA(const float* __restrict__ X,
                                          const float* __restrict__ W1_1,
                                          ushort* __restrict__ x1g,
                                          const int* __restrict__ ei0,
                                          const int* __restrict__ ei1,
                                          int* __restrict__ bh,
                                          const float* __restrict__ W1_2,
                                          const float* __restrict__ U2,
                                          const float* __restrict__ V2,
                                          const float* __restrict__ W2_2,
                                          const float* __restrict__ U1,
                                          const float* __restrict__ V1,
                                          const float* __restrict__ W2_1,
                                          ushort* __restrict__ pack5a,
                                          ushort* __restrict__ pack5b,
                                          ushort* __restrict__ pack3,
                                          int2* __restrict__ ecsr0, int2* __restrict__ ecsr1,
                                          int* __restrict__ rp0, int* __restrict__ rp1) {
    __shared__ __align__(16) char smem[64 * 132 * 4 + 4096];
    int t = threadIdx.x;
    if (blockIdx.x >= K1B + 2 * NB1) {
        if (blockIdx.x == K1B + 2 * NB1) {
            // pack5a/b + sentinels + rp ends
            for (int i = t; i < 1024; i += 256) {
                int k = i >> 6, j = i & 63;
                float su = 0.f, sv = 0.f;
                for (int m = 0; m < 64; ++m) {
                    float wm = W1_2[k * 64 + m];
                    su += wm * U2[m * 64 + j];
                    sv += wm * V2[m * 64 + j];
                }
                sv *= W2_2[j];
                int jt = j >> 4;
                int l1 = (k >> 3) * 16 + (j & 15);
                int l2 = (2 + (k >> 3)) * 16 + (j & 15);
                int e = k & 7;
                pack5a[(jt * 64 + l1) * 8 + e] = f2bf(su);
                pack5a[(jt * 64 + l2) * 8 + e] = f2bf(sv);
                pack5b[(jt * 64 + l1) * 8 + e] = f2bf(W1_2[k * 64 + j]);
                pack5b[(jt * 64 + l2) * 8 + e] = 0;
            }
            if (t < 16) { ecsr0[EE + t] = make_int2(0, 0); ecsr1[EE + t] = make_int2(0, 0); }
            if (t == 16) rp0[NN] = EE;
            if (t == 17) rp1[NN] = EE;
        } else {
            // pack3
            for (int i = t; i < 512; i += 256) {
                int e = i & 7, l = i >> 3;
                int kk = ((l >> 4) & 3) * 8 + e, h = l & 15;
                float v = (kk < 16) ? U1[kk * 16 + h] : V1[(kk - 16) * 16 + h] * W2_1[h];
                pack3[i] = f2bf(v);
            }
        }
        return;
    }
    if (blockIdx.x >= K1B) {
        // ---- passA ----
        int bp = blockIdx.x - K1B;
        int l = bp >= NB1;
        int b = bp - l * NB1;
        const int* dst = (l ? ei1 : ei0) + EE;
        int* hist = (int*)smem;
        for (int i = t; i < NBUK; i += 256) hist[i] = 0;
        __syncthreads();
        long base = (long)b * 2048;
#pragma unroll
        for (int k = 0; k < 8; ++k) {
            long i = base + k * 256 + t;
            if (i < EE) atomicAdd(&hist[dst[i] >> 8], 1);
        }
        __syncthreads();
        int* bhl = bh + (long)l * NBUK * NB1;
        for (int h = t; h < NBUK; h += 256) bhl[h * NB1 + b] = hist[h];
        return;
    }
    // ---- k1 MFMA GEMM ----
    float (*Xs)[132] = (float(*)[132])smem;
    ushort* Ws = (ushort*)(smem + 64 * 132 * 4);
    int w = t >> 6, lane = t & 63;
    int nb = blockIdx.x * 16;
    for (int i = t; i < 2048; i += 256) {
        int e = i & 7, l = (i >> 3) & 63, s = i >> 9;
        Ws[i] = f2bf(W1_1[(s * 32 + ((l >> 4) & 3) * 8 + e) * 16 + (l & 15)]);
    }
#pragma unroll
    for (int i = 0; i < 8; ++i) {
        int flat = i * 256 + t;
        int n_loc = flat >> 7;
        int b = (flat >> 5) & 3;
        int c4 = (flat & 31) << 2;
        float4 v = *reinterpret_cast<const float4*>(&X[((long)b * NN + (nb + n_loc)) * 128 + c4]);
        *reinterpret_cast<float4*>(&Xs[n_loc * 4 + b][c4]) = v;
    }
    __syncthreads();
    int arow = lane & 15, q = lane >> 4;
    floatx4 acc = {0.f, 0.f, 0.f, 0.f};
#pragma unroll
    for (int s = 0; s < 4; ++s) {
        const float* xp = &Xs[w * 16 + arow][s * 32 + q * 8];
        float4 xa = *reinterpret_cast<const float4*>(xp);
        float4 xb = *reinterpret_cast<const float4*>(xp + 4);
        FragU a;
        a.u[0] = ((uint)f2bf(xa.y) << 16) | f2bf(xa.x);
        a.u[1] = ((uint)f2bf(xa.w) << 16) | f2bf(xa.z);
        a.u[2] = ((uint)f2bf(xb.y) << 16) | f2bf(xb.x);
        a.u[3] = ((uint)f2bf(xb.w) << 16) | f2bf(xb.z);
        short8 bfrag = *reinterpret_cast<const short8*>(&Ws[(s * 64 + lane) * 8]);
        acc = __builtin_amdgcn_mfma_f32_16x16x32_bf16(a.s, bfrag, acc, 0, 0, 0);
    }
    int nw = nb + w * 4;
#pragma unroll
    for (int r = 0; r < 4; ++r) {
        int i = q * 4 + r;
        x1g[(long)(nw + (i >> 2)) * 64 + (i & 3) * 16 + (lane & 15)] = f2bf(acc[r]);
    }
}

// ---------------- passB: per-bucket exclusive scan over blocks -> cursors + colsum ----------------
__global__ __launch_bounds__(256) void passB(int* __restrict__ bh, int* __restrict__ colsum) {
    int l = blockIdx.x >= NBUK;
    int h = blockIdx.x - l * NBUK;
    int* row = bh + ((long)l * NBUK + h) * NB1;
    int t = threadIdx.x;
    int v[4];
    int s = 0;
    int b0 = t * 4;
#pragma unroll
    for (int j = 0; j < 4; ++j) {
        int b = b0 + j;
        int x = (b < NB1) ? row[b] : 0;
        v[j] = x;
        s += x;
    }
    __shared__ int wsum[4], wpre[4];
    int run = blockScanExcl(s, wsum, wpre);
#pragma unroll
    for (int j = 0; j < 4; ++j) {
        int b = b0 + j;
        if (b < NB1) row[b] = run;
        run += v[j];
    }
    if (t == 255) colsum[l * NBUK + h] = run;
}

// ---------------- gbscan: bucket offsets per list (2 blocks) ----------------
__global__ __launch_bounds__(256) void gbscan(const int* __restrict__ colsum, int* __restrict__ gb) {
    int l = blockIdx.x;
    int t = threadIdx.x;
    const int* cs = colsum + l * NBUK;
    int v[2];
    int s = 0;
#pragma unroll
    for (int j = 0; j < 2; ++j) {
        int i = t * 2 + j;
        int x = (i < NBUK) ? cs[i] : 0;
        v[j] = x;
        s += x;
    }
    __shared__ int wsum[4], wpre[4];
    int run = blockScanExcl(s, wsum, wpre);
    int* g = gb + l * 392;
#pragma unroll
    for (int j = 0; j < 2; ++j) {
        int i = t * 2 + j;
        if (i < NBUK) g[i] = run;
        run += v[j];
    }
    if (t == 255) g[NBUK] = run;  // = EE
}

// ---------------- passC0: list-0 scatter ----------------
__global__ __launch_bounds__(256) void passC0(const int* __restrict__ ei0, const float* __restrict__ ew0,
                                              const int* __restrict__ bh, const int* __restrict__ gb,
                                              int2* __restrict__ tmp) {
    __shared__ int cur[NBUK];
    passC_body(ei0, ew0, bh, gb, tmp, blockIdx.x, cur);
}

// ---------------- fuseDC: passD(list0) ∪ passC(list1) ----------------
__global__ __launch_bounds__(256) void fuseDC(const int* __restrict__ gb, int2* __restrict__ tmp,
                                              int2* __restrict__ ecsr0, int* __restrict__ rp0,
                                              const int* __restrict__ ei1, const float* __restrict__ ew1,
                                              const int* __restrict__ bh) {
    __shared__ int sh[NBUK];  // union: passD hist(256) / passC cur(NBUK)
    __shared__ int wsum[4], wpre[4];
    if (blockIdx.x < NBUK) {
        passD_body(gb, tmp, ecsr0, rp0, blockIdx.x, sh, wsum, wpre);
    } else {
        passC_body(ei1, ew1, bh + (long)NBUK * NB1, gb + 392, tmp + (long)EE,
                   blockIdx.x - NBUK, sh);
    }
}

// ---------------- k3 body: merged-range prefix-gather + MFMA epilogue (4 nodes/wave) ----------------
__device__ __forceinline__ void k3_body(const ushort* __restrict__ x1g,
                                        const int2* __restrict__ ecsr0,
                                        const int* __restrict__ rp0,
                                        const ushort* __restrict__ pack3,
                                        ushort* __restrict__ h1g,
                                        ushort (*xg)[16][40], int blk) {
    int t = threadIdx.x;
    int w = t >> 6, lane = t & 63;
    int b = lane >> 4;
    int nb = blk * 16 + w * 4;
    const char* xb = (const char*)x1g;
    int lb = lane << 1;
    int s0 = rp0[nb], b1 = rp0[nb + 1], b2 = rp0[nb + 2], b3 = rp0[nb + 3], s4 = rp0[nb + 4];
    // prefix accumulators: p0: gi<b1, p1: gi<b2, p2: gi<b3, p3: all
    float p0 = 0.f, p1 = 0.f, p2 = 0.f, p3 = 0.f;
    int e = s0;
    int efull = s0 + ((s4 - s0) & ~15);
    for (; e < efull; e += 16) {  // full chunks: no s4 mask
        int2 r[16];
#pragma unroll
        for (int i = 0; i < 16; ++i) r[i] = ecsr0[e + i];
        float v[16];
#pragma unroll
        for (int i = 0; i < 16; ++i)
            v[i] = bf2f(*(const ushort*)(xb + (uint)r[i].x + lb));
#pragma unroll
        for (int i = 0; i < 16; ++i) {
            int gi = e + i;  // wave-uniform
            float c = __int_as_float(r[i].y) * v[i];
            p0 += (gi < b1) ? c : 0.f;
            p1 += (gi < b2) ? c : 0.f;
            p2 += (gi < b3) ? c : 0.f;
            p3 += c;
        }
    }
    if (e < s4) {  // masked tail (memory-safe via global pad)
        int2 r[16];
#pragma unroll
        for (int i = 0; i < 16; ++i) r[i] = ecsr0[e + i];
        float v[16];
#pragma unroll
        for (int i = 0; i < 16; ++i)
            v[i] = bf2f(*(const ushort*)(xb + (uint)r[i].x + lb));
#pragma unroll
        for (int i = 0; i < 16; ++i) {
            int gi = e + i;
            float c = (gi < s4) ? __int_as_float(r[i].y) * v[i] : 0.f;
            p0 += (gi < b1) ? c : 0.f;
            p1 += (gi < b2) ? c : 0.f;
            p2 += (gi < b3) ? c : 0.f;
            p3 += c;
        }
    }
    float a0 = p0, a1 = p1 - p0, a2 = p2 - p1, a3 = p3 - p2;
    int h = lane & 15;
    xg[w][0 * 4 + b][16 + h] = f2bf(a0 / fmaxf((float)(b1 - s0), 1.f));
    xg[w][1 * 4 + b][16 + h] = f2bf(a1 / fmaxf((float)(b2 - b1), 1.f));
    xg[w][2 * 4 + b][16 + h] = f2bf(a2 / fmaxf((float)(b3 - b2), 1.f));
    xg[w][3 * 4 + b][16 + h] = f2bf(a3 / fmaxf((float)(s4 - b3), 1.f));
#pragma unroll
    for (int j = 0; j < 4; ++j)
        xg[w][j * 4 + b][h] = x1g[(long)(nb + j) * 64 + lane];
    short8 afrag = *reinterpret_cast<const short8*>(&xg[w][lane & 15][(lane >> 4) * 8]);
    short8 bfrag = *reinterpret_cast<const short8*>(&pack3[lane * 8]);
    floatx4 a4 = {0.f, 0.f, 0.f, 0.f};
    a4 = __builtin_amdgcn_mfma_f32_16x16x32_bf16(afrag, bfrag, a4, 0, 0, 0);
    float s = 0.f, s2 = 0.f;
#pragma unroll
    for (int r = 0; r < 4; ++r) { s += a4[r]; s2 += a4[r] * a4[r]; }
#pragma unroll
    for (int off = 1; off <= 8; off <<= 1) {
        s += __shfl_xor(s, off, 64);
        s2 += __shfl_xor(s2, off, 64);
    }
    float mean = s * (1.f / 64.f);
    float var = s2 * (1.f / 64.f) - mean * mean;
    float rs = rsqrtf(var + EPS);
    int node = lane >> 4;
#pragma unroll
    for (int r = 0; r < 4; ++r) {
        float xv = bf2f(xg[w][node * 4 + r][lane & 15]);
        float hv = xv + fmaxf((a4[r] - mean) * rs, 0.f);
        h1g[(long)(nb + node) * 64 + r * 16 + (lane & 15)] = f2bf(hv);
    }
}

// ---------------- fuseKD: k3 ∪ passD(list1) ----------------
__global__ __launch_bounds__(256) void fuseKD(const ushort* __restrict__ x1g,
                                              const int2* __restrict__ ecsr0,
                                              const int* __restrict__ rp0,
                                              const ushort* __restrict__ pack3,
                                              ushort* __restrict__ h1g,
                                              const int* __restrict__ gb,
                                              const int2* __restrict__ tmp,
                                              int2* __restrict__ ecsr1,
                                              int* __restrict__ rp1) {
    __shared__ ushort xg[4][16][40];
    __shared__ int hist[256];
    __shared__ int wsum[4], wpre[4];
    if (blockIdx.x < K1B) {
        k3_body(x1g, ecsr0, rp0, pack3, h1g, xg, blockIdx.x);
    } else {
        passD_body(gb + 392, tmp + (long)EE, ecsr1, rp1, blockIdx.x - K1B, hist, wsum, wpre);
    }
}

// ---------------- k5: merged-range prefix-gather + dual-MFMA epilogue -> out ----------------
__global__ __launch_bounds__(256) void k5(const ushort* __restrict__ h1g,
                                          const int2* __restrict__ ecsr1,
                                          const int* __restrict__ rp1,
                                          const ushort* __restrict__ pack5a,
                                          const ushort* __restrict__ pack5b,
                                          float* __restrict__ out) {
    __shared__ ushort hg[4][16][40];
    int t = threadIdx.x;
    int w = t >> 6, lane = t & 63;
    int b = lane >> 4;
    int nb = blockIdx.x * 16 + w * 4;
    const char* hb = (const char*)h1g;
    int lb = lane << 1;
    int s0 = rp1[nb], b1 = rp1[nb + 1], b2 = rp1[nb + 2], b3 = rp1[nb + 3], s4 = rp1[nb + 4];
    float p0 = 0.f, p1 = 0.f, p2 = 0.f, p3 = 0.f;
    int e = s0;
    int efull = s0 + ((s4 - s0) & ~15);
    for (; e < efull; e += 16) {  // full chunks: no s4 mask
        int2 r[16];
#pragma unroll
        for (int i = 0; i < 16; ++i) r[i] = ecsr1[e + i];
        float v[16];
#pragma unroll
        for (int i = 0; i < 16; ++i)
            v[i] = bf2f(*(const ushort*)(hb + (uint)r[i].x + lb));
#pragma unroll
        for (int i = 0; i < 16; ++i) {
            int gi = e + i;  // wave-uniform
            float c = __int_as_float(r[i].y) * v[i];
            p0 += (gi < b1) ? c : 0.f;
            p1 += (gi < b2) ? c : 0.f;
            p2 += (gi < b3) ? c : 0.f;
            p3 += c;
        }
    }
    if (e < s4) {  // masked tail
        int2 r[16];
#pragma unroll
        for (int i = 0; i < 16; ++i) r[i] = ecsr1[e + i];
        float v[16];
#pragma unroll
        for (int i = 0; i < 16; ++i)
            v[i] = bf2f(*(const ushort*)(hb + (uint)r[i].x + lb));
#pragma unroll
        for (int i = 0; i < 16; ++i) {
            int gi = e + i;
            float c = (gi < s4) ? __int_as_float(r[i].y) * v[i] : 0.f;
            p0 += (gi < b1) ? c : 0.f;
            p1 += (gi < b2) ? c : 0.f;
            p2 += (gi < b3) ? c : 0.f;
            p3 += c;
        }
    }
    float a0 = p0, a1 = p1 - p0, a2 = p2 - p1, a3 = p3 - p2;
    int h = lane & 15;
    hg[w][0 * 4 + b][16 + h] = f2bf(a0 / fmaxf((float)(b1 - s0), 1.f));
    hg[w][1 * 4 + b][16 + h] = f2bf(a1 / fmaxf((float)(b2 - b1), 1.f));
    hg[w][2 * 4 + b][16 + h] = f2bf(a2 / fmaxf((float)(b3 - b2), 1.f));
    hg[w][3 * 4 + b][16 + h] = f2bf(a3 / fmaxf((float)(s4 - b3), 1.f));
#pragma unroll
    for (int j = 0; j < 4; ++j)
        hg[w][j * 4 + b][h] = h1g[(long)(nb + j) * 64 + lane];
    short8 afrag = *reinterpret_cast<const short8*>(&hg[w][lane & 15][(lane >> 4) * 8]);
    floatx4 c1[4], c2[4];
#pragma unroll
    for (int jt = 0; jt < 4; ++jt) {
        short8 bb1 = *reinterpret_cast<const short8*>(&pack5a[(jt * 64 + lane) * 8]);
        short8 bb2 = *reinterpret_cast<const short8*>(&pack5b[(jt * 64 + lane) * 8]);
        floatx4 z = {0.f, 0.f, 0.f, 0.f};
        c1[jt] = __builtin_amdgcn_mfma_f32_16x16x32_bf16(afrag, bb1, z, 0, 0, 0);
        c2[jt] = __builtin_amdgcn_mfma_f32_16x16x32_bf16(afrag, bb2, z, 0, 0, 0);
    }
    float s = 0.f, s2 = 0.f;
#pragma unroll
    for (int jt = 0; jt < 4; ++jt)
#pragma unroll
        for (int r = 0; r < 4; ++r) { float a = c1[jt][r]; s += a; s2 += a * a; }
#pragma unroll
    for (int off = 1; off <= 8; off <<= 1) {
        s += __shfl_xor(s, off, 64);
        s2 += __shfl_xor(s2, off, 64);
    }
    float mean = s * (1.f / 256.f);
    float var = s2 * (1.f / 256.f) - mean * mean;
    float rs = rsqrtf(var + EPS);
    int node = lane >> 4;
    long n = nb + node;
#pragma unroll
    for (int r = 0; r < 4; ++r)
#pragma unroll
        for (int jt = 0; jt < 4; ++jt) {
            float norm = (c1[jt][r] - mean) * rs;
            out[((long)r * NN + n) * 64 + jt * 16 + (lane & 15)] = c2[jt][r] + fmaxf(norm, 0.f);
        }
}

extern "C" void kernel_launch(void* const* d_in, const int* in_sizes, int n_in,
                              void* d_out, int out_size, void* d_ws, size_t ws_size,
                              hipStream_t stream) {
    const float* X    = (const float*)d_in[0];
    const int*   ei0  = (const int*)d_in[1];
    const float* ew0  = (const float*)d_in[2];
    const int*   ei1  = (const int*)d_in[3];
    const float* ew1  = (const float*)d_in[4];
    const float* W1_1 = (const float*)d_in[8];
    const float* W2_1 = (const float*)d_in[9];
    const float* U1   = (const float*)d_in[10];
    const float* V1   = (const float*)d_in[11];
    const float* W1_2 = (const float*)d_in[12];
    const float* W2_2 = (const float*)d_in[13];
    const float* U2   = (const float*)d_in[14];
    const float* V2   = (const float*)d_in[15];
    float* out = (float*)d_out;
    char* ws = (char*)d_ws;

    const long MB = 1000000L;
    ushort* x1g   = (ushort*)(ws + 0L);             // 12.8 MB
    ushort* h1g   = (ushort*)(ws + 13 * MB);        // 12.8 MB
    int2*   tmp   = (int2*)(ws + 26 * MB);          // 2 x 12.8 MB
    int*    bh    = (int*)(ws + 52 * MB);           // 2.45 MB
    int*    colsum= (int*)(ws + 55 * MB);           // 3.1 KB
    int*    gb    = (int*)(ws + 55 * MB + 4096);    // 3.1 KB
    int*    rp0   = (int*)(ws + 56 * MB);           // 400 KB + 4
    int*    rp1   = (int*)(ws + 57 * MB);
    int2*   ecsr0 = (int2*)(ws + 58 * MB);          // 12.8 MB + 128 B pad
    int2*   ecsr1 = (int2*)(ws + 71 * MB);          // 12.8 MB + 128 B pad
    ushort* pack3  = (ushort*)(ws + 84 * MB);       // 1 KB
    ushort* pack5a = (ushort*)(ws + 84 * MB + 8192);
    ushort* pack5b = (ushort*)(ws + 84 * MB + 16384);

    kA<<<K1B + 2 * NB1 + 2, 256, 0, stream>>>(X, W1_1, x1g, ei0, ei1, bh,
                                              W1_2, U2, V2, W2_2, U1, V1, W2_1,
                                              pack5a, pack5b, pack3, ecsr0, ecsr1, rp0, rp1);
    passB<<<2 * NBUK, 256, 0, stream>>>(bh, colsum);
    gbscan<<<2, 256, 0, stream>>>(colsum, gb);
    passC0<<<NB1, 256, 0, stream>>>(ei0, ew0, bh, gb, tmp);
    fuseDC<<<NBUK + NB1, 256, 0, stream>>>(gb, tmp, ecsr0, rp0, ei1, ew1, bh);
    fuseKD<<<K1B + NBUK, 256, 0, stream>>>(x1g, ecsr0, rp0, pack3, h1g, gb, tmp, ecsr1, rp1);
    k5<<<K1B, 256, 0, stream>>>(h1g, ecsr1, rp1, pack5a, pack5b, out);
}

// Round 17
// 286.321 us; speedup vs baseline: 1.7657x; 1.0141x over previous
//
#include <hip/hip_runtime.h>

#define NN 100000
#define EE 1600000
#define EPS 1e-5f
#define NBUK 391   // ceil(NN/256) 256-node buckets
#define NB1 782    // ceil(EE/2048) edge-blocks per list
#define K1B 6250   // k1 blocks (16 nodes each)

typedef __attribute__((ext_vector_type(8))) short short8;
typedef __attribute__((ext_vector_type(4))) float floatx4;
union FragU { uint u[4]; short8 s; };

__device__ __forceinline__ ushort f2bf(float f) {
    uint u = __float_as_uint(f);
    uint r = (u + 0x7FFF + ((u >> 16) & 1)) >> 16;  // RNE
    return (ushort)r;
}
__device__ __forceinline__ float bf2f(ushort u) {
    return __uint_as_float(((uint)u) << 16);
}
__device__ __forceinline__ uint cvtpk(float lo, float hi) {  // bf16(hi)<<16 | bf16(lo), RNE
    uint r;
    asm("v_cvt_pk_bf16_f32 %0, %1, %2" : "=v"(r) : "v"(lo), "v"(hi));
    return r;
}

// block-wide exclusive scan of 256 ints (all 256 threads must call)
__device__ __forceinline__ int blockScanExcl(int v, int* wsum, int* wpre) {
    int t = threadIdx.x, lane = t & 63, wv = t >> 6;
    int x = v;
#pragma unroll
    for (int off = 1; off < 64; off <<= 1) {
        int y = __shfl_up(x, off, 64);
        if (lane >= off) x += y;
    }
    if (lane == 63) wsum[wv] = x;
    __syncthreads();
    if (t == 0) {
        int ss = 0;
        for (int i = 0; i < 4; ++i) { wpre[i] = ss; ss += wsum[i]; }
    }
    __syncthreads();
    return wpre[wv] + x - v;
}

// ---------------- passC body: scatter one 2048-edge block into bucket-ordered tmp ----------------
__device__ __forceinline__ void passC_body(const int* __restrict__ ei, const float* __restrict__ ew,
                                           const int* __restrict__ bhl, const int* __restrict__ gbl,
                                           int2* __restrict__ tl, int b, int* cur) {
    const int* dst = ei + EE;
    int t = threadIdx.x;
    for (int h = t; h < NBUK; h += 256) cur[h] = gbl[h] + bhl[h * NB1 + b];
    __syncthreads();
    long base = (long)b * 2048;
#pragma unroll
    for (int k = 0; k < 8; ++k) {
        long i = base + k * 256 + t;
        if (i < EE) {
            int d = dst[i];
            int slot = atomicAdd(&cur[d >> 8], 1);
            tl[slot] = make_int2(ei[i] | ((d & 255) << 17), __float_as_int(ew[i]));
        }
    }
}

// ---------------- passD body (de-staged): finalize one bucket -> rp + ecsr ----------------
__device__ __forceinline__ void passD_body(const int* __restrict__ gbl, const int2* __restrict__ tl,
                                           int2* __restrict__ ecsr, int* __restrict__ rp,
                                           int h, int* hist, int* wsum, int* wpre) {
    int t = threadIdx.x;
    int base = gbl[h], size = gbl[h + 1] - base;
    hist[t] = 0;
    __syncthreads();
    for (int i = t; i < size; i += 256)
        atomicAdd(&hist[(tl[base + i].x >> 17) & 255], 1);
    __syncthreads();
    int v = hist[t];
    int excl = blockScanExcl(v, wsum, wpre);
    int node = h * 256 + t;
    if (node < NN) rp[node] = base + excl;
    __syncthreads();
    hist[t] = excl;
    __syncthreads();
    for (int i = t; i < size; i += 256) {
        int2 r = tl[base + i];
        int L = (r.x >> 17) & 255;
        int slot = base + atomicAdd(&hist[L], 1);
        ecsr[slot] = make_int2((r.x & 0x1FFFF) << 7, r.y);
    }
}

// ---------------- kH: passA histograms ∪ constant packs ----------------
__global__ __launch_bounds__(256) void kH(const int* __restrict__ ei0,
                                          const int* __restrict__ ei1,
                                          int* __restrict__ bh,
                                          const float* __restrict__ W1_2,
                                          const float* __restrict__ U2,
                                          const float* __restrict__ V2,
                                          const float* __restrict__ W2_2,
                                          const float* __restrict__ U1,
                                          const float* __restrict__ V1,
                                          const float* __restrict__ W2_1,
                                          ushort* __restrict__ pack5a,
                                          ushort* __restrict__ pack5b,
                                          ushort* __restrict__ pack3,
                                          int2* __restrict__ ecsr0, int2* __restrict__ ecsr1,
                                          int* __restrict__ rp0, int* __restrict__ rp1) {
    __shared__ int hist[NBUK];
    int t = threadIdx.x;
    if (blockIdx.x >= 2 * NB1) {
        if (blockIdx.x == 2 * NB1) {
            for (int i = t; i < 1024; i += 256) {
                int k = i >> 6, j = i & 63;
                float su = 0.f, sv = 0.f;
                for (int m = 0; m < 64; ++m) {
                    float wm = W1_2[k * 64 + m];
                    su += wm * U2[m * 64 + j];
                    sv += wm * V2[m * 64 + j];
                }
                sv *= W2_2[j];
                int jt = j >> 4;
                int l1 = (k >> 3) * 16 + (j & 15);
                int l2 = (2 + (k >> 3)) * 16 + (j & 15);
                int e = k & 7;
                pack5a[(jt * 64 + l1) * 8 + e] = f2bf(su);
                pack5a[(jt * 64 + l2) * 8 + e] = f2bf(sv);
                pack5b[(jt * 64 + l1) * 8 + e] = f2bf(W1_2[k * 64 + j]);
                pack5b[(jt * 64 + l2) * 8 + e] = 0;
            }
            if (t < 16) { ecsr0[EE + t] = make_int2(0, 0); ecsr1[EE + t] = make_int2(0, 0); }
            if (t == 16) rp0[NN] = EE;
            if (t == 17) rp1[NN] = EE;
        } else {
            for (int i = t; i < 512; i += 256) {
                int e = i & 7, l = i >> 3;
                int kk = ((l >> 4) & 3) * 8 + e, h = l & 15;
                float v = (kk < 16) ? U1[kk * 16 + h] : V1[(kk - 16) * 16 + h] * W2_1[h];
                pack3[i] = f2bf(v);
            }
        }
        return;
    }
    int l = blockIdx.x >= NB1;
    int b = blockIdx.x - l * NB1;
    const int* dst = (l ? ei1 : ei0) + EE;
    for (int i = t; i < NBUK; i += 256) hist[i] = 0;
    __syncthreads();
    long base = (long)b * 2048;
#pragma unroll
    for (int k = 0; k < 8; ++k) {
        long i = base + k * 256 + t;
        if (i < EE) atomicAdd(&hist[dst[i] >> 8], 1);
    }
    __syncthreads();
    int* bhl = bh + (long)l * NBUK * NB1;
    for (int h = t; h < NBUK; h += 256) bhl[h * NB1 + b] = hist[h];
}

// ---------------- passB: per-bucket exclusive scan over blocks -> cursors + colsum ----------------
__global__ __launch_bounds__(256) void passB(int* __restrict__ bh, int* __restrict__ colsum) {
    int l = blockIdx.x >= NBUK;
    int h = blockIdx.x - l * NBUK;
    int* row = bh + ((long)l * NBUK + h) * NB1;
    int t = threadIdx.x;
    int v[4];
    int s = 0;
    int b0 = t * 4;
#pragma unroll
    for (int j = 0; j < 4; ++j) {
        int b = b0 + j;
        int x = (b < NB1) ? row[b] : 0;
        v[j] = x;
        s += x;
    }
    __shared__ int wsum[4], wpre[4];
    int run = blockScanExcl(s, wsum, wpre);
#pragma unroll
    for (int j = 0; j < 4; ++j) {
        int b = b0 + j;
        if (b < NB1) row[b] = run;
        run += v[j];
    }
    if (t == 255) colsum[l * NBUK + h] = run;
}

// ---------------- gbscan: bucket offsets per list (2 blocks) ----------------
__global__ __launch_bounds__(256) void gbscan(const int* __restrict__ colsum, int* __restrict__ gb) {
    int l = blockIdx.x;
    int t = threadIdx.x;
    const int* cs = colsum + l * NBUK;
    int v[2];
    int s = 0;
#pragma unroll
    for (int j = 0; j < 2; ++j) {
        int i = t * 2 + j;
        int x = (i < NBUK) ? cs[i] : 0;
        v[j] = x;
        s += x;
    }
    __shared__ int wsum[4], wpre[4];
    int run = blockScanExcl(s, wsum, wpre);
    int* g = gb + l * 392;
#pragma unroll
    for (int j = 0; j < 2; ++j) {
        int i = t * 2 + j;
        if (i < NBUK) g[i] = run;
        run += v[j];
    }
    if (t == 255) g[NBUK] = run;  // = EE
}

// ---------------- kGC: k1 MFMA GEMM ∪ passC(list0) ----------------
__global__ __launch_bounds__(256) void kGC(const float* __restrict__ X,
                                           const float* __restrict__ W1_1,
                                           ushort* __restrict__ x1g,
                                           const int* __restrict__ ei0, const float* __restrict__ ew0,
                                           const int* __restrict__ bh, const int* __restrict__ gb,
                                           int2* __restrict__ tmp) {
    __shared__ __align__(16) char smem[64 * 132 * 4 + 4096];
    int t = threadIdx.x;
    if (blockIdx.x >= K1B) {
        int* cur = (int*)smem;
        passC_body(ei0, ew0, bh, gb, tmp, blockIdx.x - K1B, cur);
        return;
    }
    float (*Xs)[132] = (float(*)[132])smem;
    ushort* Ws = (ushort*)(smem + 64 * 132 * 4);
    int w = t >> 6, lane = t & 63;
    int nb = blockIdx.x * 16;
    for (int i = t; i < 2048; i += 256) {
        int e = i & 7, l = (i >> 3) & 63, s = i >> 9;
        Ws[i] = f2bf(W1_1[(s * 32 + ((l >> 4) & 3) * 8 + e) * 16 + (l & 15)]);
    }
#pragma unroll
    for (int i = 0; i < 8; ++i) {
        int flat = i * 256 + t;
        int n_loc = flat >> 7;
        int b = (flat >> 5) & 3;
        int c4 = (flat & 31) << 2;
        float4 v = *reinterpret_cast<const float4*>(&X[((long)b * NN + (nb + n_loc)) * 128 + c4]);
        *reinterpret_cast<float4*>(&Xs[n_loc * 4 + b][c4]) = v;
    }
    __syncthreads();
    int arow = lane & 15, q = lane >> 4;
    floatx4 acc = {0.f, 0.f, 0.f, 0.f};
#pragma unroll
    for (int s = 0; s < 4; ++s) {
        const float* xp = &Xs[w * 16 + arow][s * 32 + q * 8];
        float4 xa = *reinterpret_cast<const float4*>(xp);
        float4 xb = *reinterpret_cast<const float4*>(xp + 4);
        FragU a;
        a.u[0] = cvtpk(xa.x, xa.y);
        a.u[1] = cvtpk(xa.z, xa.w);
        a.u[2] = cvtpk(xb.x, xb.y);
        a.u[3] = cvtpk(xb.z, xb.w);
        short8 bfrag = *reinterpret_cast<const short8*>(&Ws[(s * 64 + lane) * 8]);
        acc = __builtin_amdgcn_mfma_f32_16x16x32_bf16(a.s, bfrag, acc, 0, 0, 0);
    }
    int nw = nb + w * 4;
#pragma unroll
    for (int r = 0; r < 4; ++r) {
        int i = q * 4 + r;
        x1g[(long)(nw + (i >> 2)) * 64 + (i & 3) * 16 + (lane & 15)] = f2bf(acc[r]);
    }
}

// ---------------- fuseDC: passD(list0) ∪ passC(list1) ----------------
__global__ __launch_bounds__(256) void fuseDC(const int* __restrict__ gb, int2* __restrict__ tmp,
                                              int2* __restrict__ ecsr0, int* __restrict__ rp0,
                                              const int* __restrict__ ei1, const float* __restrict__ ew1,
                                              const int* __restrict__ bh) {
    __shared__ int sh[NBUK];
    __shared__ int wsum[4], wpre[4];
    if (blockIdx.x < NBUK) {
        passD_body(gb, tmp, ecsr0, rp0, blockIdx.x, sh, wsum, wpre);
    } else {
        passC_body(ei1, ew1, bh + (long)NBUK * NB1, gb + 392, tmp + (long)EE,
                   blockIdx.x - NBUK, sh);
    }
}

// ---------------- k3 body: merged-range prefix-gather + MFMA epilogue (4 nodes/wave) ----------------
__device__ __forceinline__ void k3_body(const ushort* __restrict__ x1g,
                                        const int2* __restrict__ ecsr0,
                                        const int* __restrict__ rp0,
                                        const ushort* __restrict__ pack3,
                                        ushort* __restrict__ h1g,
                                        ushort (*xg)[16][40], int blk) {
    int t = threadIdx.x;
    int w = t >> 6, lane = t & 63;
    int b = lane >> 4;
    int nb = blk * 16 + w * 4;
    const char* xb = (const char*)x1g;
    int lb = lane << 1;
    int s0 = rp0[nb], b1 = rp0[nb + 1], b2 = rp0[nb + 2], b3 = rp0[nb + 3], s4 = rp0[nb + 4];
    float p0 = 0.f, p1 = 0.f, p2 = 0.f, p3 = 0.f;
    int e = s0;
    int efull = s0 + ((s4 - s0) & ~15);
    for (; e < efull; e += 16) {
        int2 r[16];
#pragma unroll
        for (int i = 0; i < 16; ++i) r[i] = ecsr0[e + i];
        float v[16];
#pragma unroll
        for (int i = 0; i < 16; ++i)
            v[i] = bf2f(*(const ushort*)(xb + (uint)r[i].x + lb));
#pragma unroll
        for (int i = 0; i < 16; ++i) {
            int gi = e + i;
            float c = __int_as_float(r[i].y) * v[i];
            p0 += (gi < b1) ? c : 0.f;
            p1 += (gi < b2) ? c : 0.f;
            p2 += (gi < b3) ? c : 0.f;
            p3 += c;
        }
    }
    if (e < s4) {
        int2 r[16];
#pragma unroll
        for (int i = 0; i < 16; ++i) r[i] = ecsr0[e + i];
        float v[16];
#pragma unroll
        for (int i = 0; i < 16; ++i)
            v[i] = bf2f(*(const ushort*)(xb + (uint)r[i].x + lb));
#pragma unroll
        for (int i = 0; i < 16; ++i) {
            int gi = e + i;
            float c = (gi < s4) ? __int_as_float(r[i].y) * v[i] : 0.f;
            p0 += (gi < b1) ? c : 0.f;
            p1 += (gi < b2) ? c : 0.f;
            p2 += (gi < b3) ? c : 0.f;
            p3 += c;
        }
    }
    float a0 = p0, a1 = p1 - p0, a2 = p2 - p1, a3 = p3 - p2;
    int h = lane & 15;
    xg[w][0 * 4 + b][16 + h] = f2bf(a0 / fmaxf((float)(b1 - s0), 1.f));
    xg[w][1 * 4 + b][16 + h] = f2bf(a1 / fmaxf((float)(b2 - b1), 1.f));
    xg[w][2 * 4 + b][16 + h] = f2bf(a2 / fmaxf((float)(b3 - b2), 1.f));
    xg[w][3 * 4 + b][16 + h] = f2bf(a3 / fmaxf((float)(s4 - b3), 1.f));
#pragma unroll
    for (int j = 0; j < 4; ++j)
        xg[w][j * 4 + b][h] = x1g[(long)(nb + j) * 64 + lane];
    short8 afrag = *reinterpret_cast<const short8*>(&xg[w][lane & 15][(lane >> 4) * 8]);
    short8 bfrag = *reinterpret_cast<const short8*>(&pack3[lane * 8]);
    floatx4 a4 = {0.f, 0.f, 0.f, 0.f};
    a4 = __builtin_amdgcn_mfma_f32_16x16x32_bf16(afrag, bfrag, a4, 0, 0, 0);
    float s = 0.f, s2 = 0.f;
#pragma unroll
    for (int r = 0; r < 4; ++r) { s += a4[r]; s2 += a4[r] * a4[r]; }
#pragma unroll
    for (int off = 1; off <= 8; off <<= 1) {
        s += __shfl_xor(s, off, 64);
        s2 += __shfl_xor(s2, off, 64);
    }
    float mean = s * (1.f / 64.f);
    float var = s2 * (1.f / 64.f) - mean * mean;
    float rs = rsqrtf(var + EPS);
    int node = lane >> 4;
#pragma unroll
    for (int r = 0; r < 4; ++r) {
        float xv = bf2f(xg[w][node * 4 + r][lane & 15]);
        float hv = xv + fmaxf((a4[r] - mean) * rs, 0.f);
        h1g[(long)(nb + node) * 64 + r * 16 + (lane & 15)] = f2bf(hv);
    }
}

// ---------------- fuseKD: k3 ∪ passD(list1) ----------------
__global__ __launch_bounds__(256) void fuseKD(const ushort* __restrict__ x1g,
                                              const int2* __restrict__ ecsr0,
                                              const int* __restrict__ rp0,
                                              const ushort* __restrict__ pack3,
                                              ushort* __restrict__ h1g,
                                              const int* __restrict__ gb,
                                              const int2* __restrict__ tmp,
                                              int2* __restrict__ ecsr1,
                                              int* __restrict__ rp1) {
    __shared__ ushort xg[4][16][40];
    __shared__ int hist[256];
    __shared__ int wsum[4], wpre[4];
    if (blockIdx.x < K1B) {
        k3_body(x1g, ecsr0, rp0, pack3, h1g, xg, blockIdx.x);
    } else {
        passD_body(gb + 392, tmp + (long)EE, ecsr1, rp1, blockIdx.x - K1B, hist, wsum, wpre);
    }
}

// ---------------- k5: merged-range prefix-gather + dual-MFMA epilogue -> out ----------------
__global__ __launch_bounds__(256) void k5(const ushort* __restrict__ h1g,
                                          const int2* __restrict__ ecsr1,
                                          const int* __restrict__ rp1,
                                          const ushort* __restrict__ pack5a,
                                          const ushort* __restrict__ pack5b,
                                          float* __restrict__ out) {
    __shared__ ushort hg[4][16][40];
    int t = threadIdx.x;
    int w = t >> 6, lane = t & 63;
    int b = lane >> 4;
    int nb = blockIdx.x * 16 + w * 4;
    const char* hb = (const char*)h1g;
    int lb = lane << 1;
    int s0 = rp1[nb], b1 = rp1[nb + 1], b2 = rp1[nb + 2], b3 = rp1[nb + 3], s4 = rp1[nb + 4];
    float p0 = 0.f, p1 = 0.f, p2 = 0.f, p3 = 0.f;
    int e = s0;
    int efull = s0 + ((s4 - s0) & ~15);
    for (; e < efull; e += 16) {
        int2 r[16];
#pragma unroll
        for (int i = 0; i < 16; ++i) r[i] = ecsr1[e + i];
        float v[16];
#pragma unroll
        for (int i = 0; i < 16; ++i)
            v[i] = bf2f(*(const ushort*)(hb + (uint)r[i].x + lb));
#pragma unroll
        for (int i = 0; i < 16; ++i) {
            int gi = e + i;
            float c = __int_as_float(r[i].y) * v[i];
            p0 += (gi < b1) ? c : 0.f;
            p1 += (gi < b2) ? c : 0.f;
            p2 += (gi < b3) ? c : 0.f;
            p3 += c;
        }
    }
    if (e < s4) {
        int2 r[16];
#pragma unroll
        for (int i = 0; i < 16; ++i) r[i] = ecsr1[e + i];
        float v[16];
#pragma unroll
        for (int i = 0; i < 16; ++i)
            v[i] = bf2f(*(const ushort*)(hb + (uint)r[i].x + lb));
#pragma unroll
        for (int i = 0; i < 16; ++i) {
            int gi = e + i;
            float c = (gi < s4) ? __int_as_float(r[i].y) * v[i] : 0.f;
            p0 += (gi < b1) ? c : 0.f;
            p1 += (gi < b2) ? c : 0.f;
            p2 += (gi < b3) ? c : 0.f;
            p3 += c;
        }
    }
    float a0 = p0, a1 = p1 - p0, a2 = p2 - p1, a3 = p3 - p2;
    int h = lane & 15;
    hg[w][0 * 4 + b][16 + h] = f2bf(a0 / fmaxf((float)(b1 - s0), 1.f));
    hg[w][1 * 4 + b][16 + h] = f2bf(a1 / fmaxf((float)(b2 - b1), 1.f));
    hg[w][2 * 4 + b][16 + h] = f2bf(a2 / fmaxf((float)(b3 - b2), 1.f));
    hg[w][3 * 4 + b][16 + h] = f2bf(a3 / fmaxf((float)(s4 - b3), 1.f));
#pragma unroll
    for (int j = 0; j < 4; ++j)
        hg[w][j * 4 + b][h] = h1g[(long)(nb + j) * 64 + lane];
    short8 afrag = *reinterpret_cast<const short8*>(&hg[w][lane & 15][(lane >> 4) * 8]);
    floatx4 c1[4], c2[4];
#pragma unroll
    for (int jt = 0; jt < 4; ++jt) {
        short8 bb1 = *reinterpret_cast<const short8*>(&pack5a[(jt * 64 + lane) * 8]);
        short8 bb2 = *reinterpret_cast<const short8*>(&pack5b[(jt * 64 + lane) * 8]);
        floatx4 z = {0.f, 0.f, 0.f, 0.f};
        c1[jt] = __builtin_amdgcn_mfma_f32_16x16x32_bf16(afrag, bb1, z, 0, 0, 0);
        c2[jt] = __builtin_amdgcn_mfma_f32_16x16x32_bf16(afrag, bb2, z, 0, 0, 0);
    }
    float s = 0.f, s2 = 0.f;
#pragma unroll
    for (int jt = 0; jt < 4; ++jt)
#pragma unroll
        for (int r = 0; r < 4; ++r) { float a = c1[jt][r]; s += a; s2 += a * a; }
#pragma unroll
    for (int off = 1; off <= 8; off <<= 1) {
        s += __shfl_xor(s, off, 64);
        s2 += __shfl_xor(s2, off, 64);
    }
    float mean = s * (1.f / 256.f);
    float var = s2 * (1.f / 256.f) - mean * mean;
    float rs = rsqrtf(var + EPS);
    int node = lane >> 4;
    long n = nb + node;
#pragma unroll
    for (int r = 0; r < 4; ++r)
#pragma unroll
        for (int jt = 0; jt < 4; ++jt) {
            float norm = (c1[jt][r] - mean) * rs;
            out[((long)r * NN + n) * 64 + jt * 16 + (lane & 15)] = c2[jt][r] + fmaxf(norm, 0.f);
        }
}

extern "C" void kernel_launch(void* const* d_in, const int* in_sizes, int n_in,
                              void* d_out, int out_size, void* d_ws, size_t ws_size,
                              hipStream_t stream) {
    const float* X    = (const float*)d_in[0];
    const int*   ei0  = (const int*)d_in[1];
    const float* ew0  = (const float*)d_in[2];
    const int*   ei1  = (const int*)d_in[3];
    const float* ew1  = (const float*)d_in[4];
    const float* W1_1 = (const float*)d_in[8];
    const float* W2_1 = (const float*)d_in[9];
    const float* U1   = (const float*)d_in[10];
    const float* V1   = (const float*)d_in[11];
    const float* W1_2 = (const float*)d_in[12];
    const float* W2_2 = (const float*)d_in[13];
    const float* U2   = (const float*)d_in[14];
    const float* V2   = (const float*)d_in[15];
    float* out = (float*)d_out;
    char* ws = (char*)d_ws;

    const long MB = 1000000L;
    ushort* x1g   = (ushort*)(ws + 0L);             // 12.8 MB
    ushort* h1g   = (ushort*)(ws + 13 * MB);        // 12.8 MB
    int2*   tmp   = (int2*)(ws + 26 * MB);          // 2 x 12.8 MB
    int*    bh    = (int*)(ws + 52 * MB);           // 2.45 MB
    int*    colsum= (int*)(ws + 55 * MB);           // 3.1 KB
    int*    gb    = (int*)(ws + 55 * MB + 4096);    // 3.1 KB
    int*    rp0   = (int*)(ws + 56 * MB);           // 400 KB + 4
    int*    rp1   = (int*)(ws + 57 * MB);
    int2*   ecsr0 = (int2*)(ws + 58 * MB);          // 12.8 MB + 128 B pad
    int2*   ecsr1 = (int2*)(ws + 71 * MB);          // 12.8 MB + 128 B pad
    ushort* pack3  = (ushort*)(ws + 84 * MB);       // 1 KB
    ushort* pack5a = (ushort*)(ws + 84 * MB + 8192);
    ushort* pack5b = (ushort*)(ws + 84 * MB + 16384);

    kH<<<2 * NB1 + 2, 256, 0, stream>>>(ei0, ei1, bh, W1_2, U2, V2, W2_2, U1, V1, W2_1,
                                        pack5a, pack5b, pack3, ecsr0, ecsr1, rp0, rp1);
    passB<<<2 * NBUK, 256, 0, stream>>>(bh, colsum);
    gbscan<<<2, 256, 0, stream>>>(colsum, gb);
    kGC<<<K1B + NB1, 256, 0, stream>>>(X, W1_1, x1g, ei0, ew0, bh, gb, tmp);
    fuseDC<<<NBUK + NB1, 256, 0, stream>>>(gb, tmp, ecsr0, rp0, ei1, ew1, bh);
    fuseKD<<<K1B + NBUK, 256, 0, stream>>>(x1g, ecsr0, rp0, pack3, h1g, gb, tmp, ecsr1, rp1);
    k5<<<K1B, 256, 0, stream>>>(h1g, ecsr1, rp1, pack5a, pack5b, out);
}